// Round 7
// baseline (357.097 us; speedup 1.0000x reference)
//
#include <hip/hip_runtime.h>
#include <math.h>

#define D 128
#define HB 128     // histogram blocks
#define FA_PS 88   // flash P stride (shorts)
#define SPLITS 8

typedef short bf16x4 __attribute__((ext_vector_type(4)));
typedef short bf16x8 __attribute__((ext_vector_type(8)));
typedef float f32x4 __attribute__((ext_vector_type(4)));

__device__ __forceinline__ float4 ld4(const float* p) { return *(const float4*)p; }

__device__ __forceinline__ short f2bf_r(float f) {
  return (short)((__float_as_uint(f) + 0x8000u) >> 16);
}
__device__ __forceinline__ float bf2f(short s) {
  return __uint_as_float(((unsigned)(unsigned short)s) << 16);
}
__device__ __forceinline__ unsigned pack_bf2(float a, float b) {
  unsigned ua = __float_as_uint(a) + 0x8000u;
  unsigned ub = __float_as_uint(b) + 0x8000u;
  return __builtin_amdgcn_perm(ub, ua, 0x07060302);
}

// device-scope grid barrier (co-residency by capacity: HB=128 blocks <= 256 CUs)
__device__ __forceinline__ void gsync(int* bar, int target) {
  __syncthreads();
  __threadfence();
  if (threadIdx.x == 0) {
    __hip_atomic_fetch_add(bar, 1, __ATOMIC_RELEASE, __HIP_MEMORY_SCOPE_AGENT);
    while (__hip_atomic_load(bar, __ATOMIC_ACQUIRE, __HIP_MEMORY_SCOPE_AGENT) < target)
      __builtin_amdgcn_s_sleep(4);
  }
  __syncthreads();
  __threadfence();
}

// ---------------- prep0: weights + x -> bf16; zero bar/MkhI ----------------
struct WSrc { const float* p[9]; };
__global__ __launch_bounds__(256) void prep0_kernel(WSrc ws, short* __restrict__ Wbf,
                                                    const float* __restrict__ x,
                                                    short* __restrict__ xbf,
                                                    int* __restrict__ bar,
                                                    int* __restrict__ MkhI) {
  int b = blockIdx.x, t = threadIdx.x;
  if (b == 0 && t == 0) {
    *bar = 0;
    MkhI[0] = 0; MkhI[1] = 0; MkhI[2] = 0; MkhI[3] = 0;
  }
  if (b < 144) {
    int m = b >> 4, blk = b & 15;
    int i = (blk * 256 + t) * 4;
    float4 v = ld4(ws.p[m] + i);
    bf16x4 o = {f2bf_r(v.x), f2bf_r(v.y), f2bf_r(v.z), f2bf_r(v.w)};
    *(bf16x4*)&Wbf[m * 16384 + i] = o;
  } else {
    int i = ((b - 144) * 256 + t) * 4;
    float4 v = ld4(x + i);
    bf16x4 o = {f2bf_r(v.x), f2bf_r(v.y), f2bf_r(v.z), f2bf_r(v.w)};
    *(bf16x4*)&xbf[i] = o;
  }
}

// ---------------- single-dispatch CSR build (grid-barrier phased) ----------------
__global__ __launch_bounds__(256) void csr_kernel(
    const int* __restrict__ src, const int* __restrict__ dst,
    int* __restrict__ histd, int* __restrict__ hists,
    int* __restrict__ base_arr, int* __restrict__ csr_src,
    float* __restrict__ dinv, int* __restrict__ row_ptr,
    int* __restrict__ bsum, int* bar, int E, int N) {
  __shared__ int hd[8192];
  __shared__ int hs[8192];
  const int t = threadIdx.x;
  const int b = blockIdx.x;
  const int per = E / HB;
  const int b0 = b * per;
  // P0: LDS-private histograms
  for (int i = t; i < 8192; i += 256) { hd[i] = 0; hs[i] = 0; }
  __syncthreads();
  for (int j = 0; j < per; j += 256) {
    int i = b0 + j + t;
    atomicAdd(&hd[dst[i]], 1);
    atomicAdd(&hs[src[i]], 1);
  }
  __syncthreads();
  for (int i = t; i < 8192; i += 256) {
    histd[b * 8192 + i] = hd[i];
    hists[b * 8192 + i] = hs[i];
  }
  int sd = 0;
  int v = b * 64 + (t & 63);
  gsync(bar, HB);
  // P1: column sums (64 lanes own 64 columns), block total
  if (t < 64) {
    int ss = 0;
    for (int k = 0; k < HB; ++k) { sd += histd[k * 8192 + v]; ss += hists[k * 8192 + v]; }
    dinv[v] = ss > 0 ? rsqrtf((float)ss) : 0.f;
    int tot = sd;
#pragma unroll
    for (int off = 32; off; off >>= 1) tot += __shfl_xor(tot, off);
    if (t == 0) bsum[b] = tot;
  }
  gsync(bar, 2 * HB);
  // P2: cross-block prefix + intra scan + basegen
  if (t < 64) {
    int x = (t < b) ? bsum[t] : 0;
    if (t + 64 < b) x += bsum[t + 64];
#pragma unroll
    for (int off = 32; off; off >>= 1) x += __shfl_xor(x, off);
    int incl = sd;
#pragma unroll
    for (int off = 1; off < 64; off <<= 1) {
      int y = __shfl_up(incl, off);
      if ((t & 63) >= off) incl += y;
    }
    int base = x + incl - sd;
    row_ptr[v] = base;
    if (b == HB - 1 && t == 63) row_ptr[N] = x + incl;
    int run = base;
    for (int k = 0; k < HB; ++k) { base_arr[k * 8192 + v] = run; run += histd[k * 8192 + v]; }
  }
  gsync(bar, 3 * HB);
  // P3: scatter with LDS local rank
  for (int i = t; i < 8192; i += 256) hd[i] = 0;
  __syncthreads();
  const int* __restrict__ bb = &base_arr[b * 8192];
  for (int j = 0; j < per; j += 256) {
    int i = b0 + j + t;
    int vv = dst[i];
    int r = atomicAdd(&hd[vv], 1);
    csr_src[bb[vv] + r] = src[i];
  }
}

// ---------------- GCN aggregation: bf16 gather, 4 independent edge streams ----------------
__global__ __launch_bounds__(128) void agg_kernel(
    const short* __restrict__ fbf, const float* __restrict__ dinv,
    const int* __restrict__ row_ptr, const int* __restrict__ csr_src,
    short* __restrict__ outbf) {
  __shared__ int idx[128];
  __shared__ float dv[128];
  __shared__ float red[8][128];
  int n = blockIdx.x, t = threadIdx.x;
  int grp = t >> 4, l16 = t & 15;
  int beg = row_ptr[n], end = row_ptr[n + 1];
  float a0[8] = {}, a1[8] = {}, a2[8] = {}, a3[8] = {};
  for (int c = beg; c < end; c += 128) {
    int j = c + t;
    if (j < end) { int s = csr_src[j]; idx[t] = s; dv[t] = dinv[s]; }
    __syncthreads();
    int cnt = min(128, end - c);
    int e = grp;
    for (; e + 24 < cnt; e += 32) {
      bf16x8 w0 = *(const bf16x8*)&fbf[(size_t)idx[e] * D + l16 * 8];
      bf16x8 w1 = *(const bf16x8*)&fbf[(size_t)idx[e + 8] * D + l16 * 8];
      bf16x8 w2 = *(const bf16x8*)&fbf[(size_t)idx[e + 16] * D + l16 * 8];
      bf16x8 w3 = *(const bf16x8*)&fbf[(size_t)idx[e + 24] * D + l16 * 8];
      float wt0 = dv[e], wt1 = dv[e + 8], wt2 = dv[e + 16], wt3 = dv[e + 24];
#pragma unroll
      for (int k = 0; k < 8; ++k) {
        a0[k] += bf2f(w0[k]) * wt0;
        a1[k] += bf2f(w1[k]) * wt1;
        a2[k] += bf2f(w2[k]) * wt2;
        a3[k] += bf2f(w3[k]) * wt3;
      }
    }
    for (; e < cnt; e += 8) {
      bf16x8 w0 = *(const bf16x8*)&fbf[(size_t)idx[e] * D + l16 * 8];
      float wt0 = dv[e];
#pragma unroll
      for (int k = 0; k < 8; ++k) a0[k] += bf2f(w0[k]) * wt0;
    }
    __syncthreads();
  }
#pragma unroll
  for (int k = 0; k < 8; ++k) a0[k] += a1[k] + a2[k] + a3[k];
  *(float4*)&red[grp][l16 * 8] = *(float4*)&a0[0];
  *(float4*)&red[grp][l16 * 8 + 4] = *(float4*)&a0[4];
  __syncthreads();
  if (t < 32) {
    int d0 = t * 4;
    float o[4] = {};
#pragma unroll
    for (int g = 0; g < 8; ++g) {
      o[0] += red[g][d0]; o[1] += red[g][d0 + 1];
      o[2] += red[g][d0 + 2]; o[3] += red[g][d0 + 3];
    }
    float w = dinv[n];
    bf16x4 ov = {f2bf_r(o[0] * w), f2bf_r(o[1] * w), f2bf_r(o[2] * w), f2bf_r(o[3] * w)};
    *(bf16x4*)&outbf[(size_t)n * D + d0] = ov;
  }
}

// ---------------- MFMA helpers ----------------
__device__ __forceinline__ void mfma_accum(const short* As, const short* __restrict__ W,
                                           int rt, int ch, int quad, int r16, f32x4* acc) {
#pragma unroll
  for (int ks = 0; ks < 4; ++ks) {
    bf16x8 af = *(bf16x8*)&As[(rt * 16 + r16) * 136 + ks * 32 + quad * 8];
#pragma unroll
    for (int nt = 0; nt < 4; ++nt) {
      bf16x8 bw = *(const bf16x8*)&W[(size_t)(ch * 64 + nt * 16 + r16) * D + ks * 32 + quad * 8];
      acc[nt] = __builtin_amdgcn_mfma_f32_16x16x32_bf16(af, bw, acc[nt], 0, 0, 0);
    }
  }
}

__device__ __forceinline__ void stage_A_f32(const float* __restrict__ A, int m0, short* As) {
  int row = threadIdx.x >> 3, seg = threadIdx.x & 7;
  const float* ap = &A[(size_t)(m0 + row) * D + seg * 16];
  float4 v0 = ld4(ap), v1 = ld4(ap + 4), v2 = ld4(ap + 8), v3 = ld4(ap + 12);
  bf16x8 w0 = {f2bf_r(v0.x), f2bf_r(v0.y), f2bf_r(v0.z), f2bf_r(v0.w),
               f2bf_r(v1.x), f2bf_r(v1.y), f2bf_r(v1.z), f2bf_r(v1.w)};
  bf16x8 w1 = {f2bf_r(v2.x), f2bf_r(v2.y), f2bf_r(v2.z), f2bf_r(v2.w),
               f2bf_r(v3.x), f2bf_r(v3.y), f2bf_r(v3.z), f2bf_r(v3.w)};
  *(bf16x8*)&As[row * 136 + seg * 16] = w0;
  *(bf16x8*)&As[row * 136 + seg * 16 + 8] = w1;
}

__device__ __forceinline__ void stage_A_bf16(const short* __restrict__ A, int m0, short* As) {
  int row = threadIdx.x >> 3, seg = threadIdx.x & 7;
  const short* ap = &A[(size_t)(m0 + row) * D + seg * 16];
  bf16x8 a0 = *(const bf16x8*)ap;
  bf16x8 a1 = *(const bf16x8*)(ap + 8);
  *(bf16x8*)&As[row * 136 + seg * 16] = a0;
  *(bf16x8*)&As[row * 136 + seg * 16 + 8] = a1;
}

// ---------------- GCN dual GEMM ----------------
__global__ __launch_bounds__(256) void gemm_gcn_kernel(
    const short* __restrict__ A1, const short* __restrict__ W1, const float* __restrict__ b1,
    const short* __restrict__ A2, const short* __restrict__ W2, const float* __restrict__ b2,
    short* __restrict__ Cbf, float* __restrict__ Cf) {
  __shared__ short As[32 * 136];
  const int t = threadIdx.x;
  const int m0 = blockIdx.x * 32;
  const int w = t >> 6, lane = t & 63, quad = lane >> 4, r16 = lane & 15;
  const int rt = w & 1, ch = w >> 1;
  f32x4 acc[4];
  f32x4 zz = {0.f, 0.f, 0.f, 0.f};
  acc[0] = zz; acc[1] = zz; acc[2] = zz; acc[3] = zz;
  stage_A_bf16(A1, m0, As);
  __syncthreads();
  mfma_accum(As, W1, rt, ch, quad, r16, acc);
  __syncthreads();
  stage_A_bf16(A2, m0, As);
  __syncthreads();
  mfma_accum(As, W2, rt, ch, quad, r16, acc);
#pragma unroll
  for (int nt = 0; nt < 4; ++nt) {
    int col = ch * 64 + nt * 16 + r16;
    float bias = b1[col] + b2[col];
#pragma unroll
    for (int g = 0; g < 4; ++g) {
      int row = m0 + rt * 16 + quad * 4 + g;
      float v = acc[nt][g] + bias;
      if (Cbf) Cbf[(size_t)row * D + col] = f2bf_r(v);
      if (Cf) Cf[(size_t)row * D + col] = v;
    }
  }
}

// ---------------- fused QKV projections with prep epilogues ----------------
__global__ __launch_bounds__(256) void qkv_kernel(
    const float* __restrict__ B2, const float* __restrict__ seq,
    const short* __restrict__ Wq, const short* __restrict__ Wk, const short* __restrict__ Wv,
    const float* __restrict__ ipb,
    short* __restrict__ Qbf, float* __restrict__ qn,
    short* __restrict__ Kbf, int* __restrict__ MkhI,
    short* __restrict__ Vt, int N, int S) {
  __shared__ short As[32 * 136];
  __shared__ int lmax[4];
  const int t = threadIdx.x;
  const int b = blockIdx.x;
  const int w = t >> 6, lane = t & 63, quad = lane >> 4, r16 = lane & 15;
  const int rt = w & 1, ch = w >> 1;
  if (t < 4) lmax[t] = 0;
  f32x4 acc[4];
  f32x4 zz = {0.f, 0.f, 0.f, 0.f};
  acc[0] = zz; acc[1] = zz; acc[2] = zz; acc[3] = zz;
  const float SC = 0.25503473f;   // (1/sqrt(32)) * log2(e)

  if (b < 256) {
    int m0 = b * 32;
    stage_A_f32(B2, m0, As);
    __syncthreads();
    mfma_accum(As, Wq, rt, ch, quad, r16, acc);
    float pq[4][2] = {};
#pragma unroll
    for (int nt = 0; nt < 4; ++nt) {
      int col = ch * 64 + nt * 16 + r16;
      float bias = ipb[col];
      int p = nt >> 1;
#pragma unroll
      for (int g = 0; g < 4; ++g) {
        int row = m0 + rt * 16 + quad * 4 + g;
        float vs = (acc[nt][g] + bias) * SC;
        Qbf[(size_t)row * D + col] = f2bf_r(vs);
        pq[g][p] += vs * vs;
      }
    }
#pragma unroll
    for (int mask = 1; mask < 16; mask <<= 1)
#pragma unroll
      for (int g = 0; g < 4; ++g) {
        pq[g][0] += __shfl_xor(pq[g][0], mask);
        pq[g][1] += __shfl_xor(pq[g][1], mask);
      }
    if (r16 == 0) {
#pragma unroll
      for (int g = 0; g < 4; ++g) {
        int row = m0 + rt * 16 + quad * 4 + g;
        qn[(ch * 2 + 0) * N + row] = sqrtf(pq[g][0]);
        qn[(ch * 2 + 1) * N + row] = sqrtf(pq[g][1]);
      }
    }
  } else if (b < 320) {
    int m0 = (b - 256) * 32;
    stage_A_f32(seq, m0, As);
    __syncthreads();
    mfma_accum(As, Wk, rt, ch, quad, r16, acc);
    float pk[4][2] = {};
#pragma unroll
    for (int nt = 0; nt < 4; ++nt) {
      int col = ch * 64 + nt * 16 + r16;
      float bias = ipb[128 + col];
      int p = nt >> 1;
#pragma unroll
      for (int g = 0; g < 4; ++g) {
        int key = m0 + rt * 16 + quad * 4 + g;
        float v = acc[nt][g] + bias;
        Kbf[(size_t)key * D + col] = f2bf_r(v);
        pk[g][p] += v * v;
      }
    }
#pragma unroll
    for (int mask = 1; mask < 16; mask <<= 1)
#pragma unroll
      for (int g = 0; g < 4; ++g) {
        pk[g][0] += __shfl_xor(pk[g][0], mask);
        pk[g][1] += __shfl_xor(pk[g][1], mask);
      }
    if (r16 == 0) {
#pragma unroll
      for (int g = 0; g < 4; ++g) {
        atomicMax(&lmax[ch * 2 + 0], __float_as_int(pk[g][0]));
        atomicMax(&lmax[ch * 2 + 1], __float_as_int(pk[g][1]));
      }
    }
    __syncthreads();
    if (t < 4) atomicMax(&MkhI[t], lmax[t]);
  } else {
    int m0 = (b - 320) * 32;
    stage_A_f32(seq, m0, As);
    __syncthreads();
    mfma_accum(As, Wv, rt, ch, quad, r16, acc);
#pragma unroll
    for (int nt = 0; nt < 4; ++nt) {
      int dim = ch * 64 + nt * 16 + r16;
      float bias = ipb[256 + dim];
#pragma unroll
      for (int g = 0; g < 4; ++g) {
        int s = m0 + rt * 16 + quad * 4 + g;
        int local = s & 63;
        int kp = (local & 15) * 4 + (local >> 4);     // key' permutation
        int gcol = (s & ~63) + kp;
        Vt[(size_t)dim * S + gcol] = f2bf_r(acc[nt][g] + bias);
      }
    }
  }
}

// ---------------- MFMA flash attention: fixed-shift (log2), split-S=8, permuted P ----------------
__global__ __launch_bounds__(64, 8) void flash_kernel(
    const short* __restrict__ Qbf, const short* __restrict__ Kbf, const short* __restrict__ Vt,
    const float* __restrict__ qn, const int* __restrict__ MkhI,
    float* __restrict__ Osp, float* __restrict__ lbuf, int N, int S) {
  __shared__ short Ps[32 * FA_PS];
  const int lane = threadIdx.x;
  const int quad = lane >> 4, r16 = lane & 15;
  const int n0 = blockIdx.x * 32;
  const int h = blockIdx.y;
  const int sp = blockIdx.z;
  float* O = Osp + (size_t)sp * N * D;

  bf16x8 aq[2];
  aq[0] = *(const bf16x8*)&Qbf[(size_t)(n0 + r16) * D + h * 32 + quad * 8];
  aq[1] = *(const bf16x8*)&Qbf[(size_t)(n0 + 16 + r16) * D + h * 32 + quad * 8];

  float sqm = sqrtf(fmaxf(__int_as_float(MkhI[h]), 0.f));
  float msh[2][4];
#pragma unroll
  for (int rt = 0; rt < 2; ++rt)
#pragma unroll
    for (int g = 0; g < 4; ++g)
      msh[rt][g] = fminf(qn[h * N + n0 + rt * 16 + quad * 4 + g] * sqm, 57.7f);

  f32x4 o[2][2], lac[2];
  f32x4 zz = {0.f, 0.f, 0.f, 0.f};
  o[0][0] = zz; o[0][1] = zz; o[1][0] = zz; o[1][1] = zz;
  lac[0] = zz; lac[1] = zz;
  bf16x8 ones = {(short)0x3F80, (short)0x3F80, (short)0x3F80, (short)0x3F80,
                 (short)0x3F80, (short)0x3F80, (short)0x3F80, (short)0x3F80};

  const int span = S / SPLITS;
  const int c0 = sp * span;
  for (int c = c0; c < c0 + span; c += 64) {
    f32x4 s[2][4];
#pragma unroll
    for (int kt = 0; kt < 4; ++kt) {
      bf16x8 bk = *(const bf16x8*)&Kbf[(size_t)(c + kt * 16 + r16) * D + h * 32 + quad * 8];
      f32x4 z = {0.f, 0.f, 0.f, 0.f};
      s[0][kt] = __builtin_amdgcn_mfma_f32_16x16x32_bf16(aq[0], bk, z, 0, 0, 0);
      s[1][kt] = __builtin_amdgcn_mfma_f32_16x16x32_bf16(aq[1], bk, z, 0, 0, 0);
    }
#pragma unroll
    for (int rt = 0; rt < 2; ++rt)
#pragma unroll
      for (int g = 0; g < 4; ++g) {
        float m = msh[rt][g];
        float p0 = exp2f(s[rt][0][g] - m);
        float p1 = exp2f(s[rt][1][g] - m);
        float p2 = exp2f(s[rt][2][g] - m);
        float p3 = exp2f(s[rt][3][g] - m);
        uint2 uv = {pack_bf2(p0, p1), pack_bf2(p2, p3)};
        *(uint2*)&Ps[(rt * 16 + quad * 4 + g) * FA_PS + r16 * 4] = uv;
      }
    bf16x8 bv[2][2];
#pragma unroll
    for (int kc = 0; kc < 2; ++kc)
#pragma unroll
      for (int nt = 0; nt < 2; ++nt)
        bv[kc][nt] = *(const bf16x8*)&Vt[(size_t)(h * 32 + nt * 16 + r16) * S + c + kc * 32 + quad * 8];
#pragma unroll
    for (int rt = 0; rt < 2; ++rt)
#pragma unroll
      for (int kc = 0; kc < 2; ++kc) {
        bf16x8 ap = *(bf16x8*)&Ps[(rt * 16 + r16) * FA_PS + kc * 32 + quad * 8];
        lac[rt] = __builtin_amdgcn_mfma_f32_16x16x32_bf16(ap, ones, lac[rt], 0, 0, 0);
#pragma unroll
        for (int nt = 0; nt < 2; ++nt)
          o[rt][nt] = __builtin_amdgcn_mfma_f32_16x16x32_bf16(ap, bv[kc][nt], o[rt][nt], 0, 0, 0);
      }
  }
#pragma unroll
  for (int rt = 0; rt < 2; ++rt)
#pragma unroll
    for (int g = 0; g < 4; ++g) {
      int row = n0 + rt * 16 + quad * 4 + g;
#pragma unroll
      for (int nt = 0; nt < 2; ++nt)
        O[(size_t)row * D + h * 32 + nt * 16 + r16] = o[rt][nt][g];
      if (r16 == 0) lbuf[(sp * 4 + h) * N + row] = lac[rt][g];
    }
}

// ---------------- out_proj GEMM: fused split-merge + residual + LN + L2 ----------------
__global__ __launch_bounds__(256) void gemm_op_kernel(
    const float* __restrict__ Osp, const float* __restrict__ lbuf,
    const short* __restrict__ W, const float* __restrict__ bias,
    const float* __restrict__ Rres, const float* __restrict__ ln_g,
    const float* __restrict__ ln_b, float* __restrict__ emb, int N) {
  __shared__ short As[32 * 136];
  __shared__ float Cs[32 * 132];
  const int t = threadIdx.x;
  const int m0 = blockIdx.x * 32;
  const int w = t >> 6, lane = t & 63, quad = lane >> 4, r16 = lane & 15;
  const int rt = w & 1, ch = w >> 1;
  {
    int row = t >> 3, seg = t & 7;
    int grow = m0 + row;
    int hh = seg >> 1;
    float l = 0.f;
#pragma unroll
    for (int s = 0; s < SPLITS; ++s) l += lbuf[(s * 4 + hh) * N + grow];
    float inv = 1.f / l;
    const float* p = &Osp[(size_t)grow * D + seg * 16];
    size_t st = (size_t)N * D;
    float a16[16] = {};
#pragma unroll
    for (int s = 0; s < SPLITS; ++s) {
#pragma unroll
      for (int q = 0; q < 4; ++q) {
        float4 a = ld4(p + s * st + q * 4);
        a16[q * 4 + 0] += a.x; a16[q * 4 + 1] += a.y;
        a16[q * 4 + 2] += a.z; a16[q * 4 + 3] += a.w;
      }
    }
#pragma unroll
    for (int k = 0; k < 16; ++k) a16[k] *= inv;
    bf16x8 w0 = {f2bf_r(a16[0]), f2bf_r(a16[1]), f2bf_r(a16[2]), f2bf_r(a16[3]),
                 f2bf_r(a16[4]), f2bf_r(a16[5]), f2bf_r(a16[6]), f2bf_r(a16[7])};
    bf16x8 w1 = {f2bf_r(a16[8]), f2bf_r(a16[9]), f2bf_r(a16[10]), f2bf_r(a16[11]),
                 f2bf_r(a16[12]), f2bf_r(a16[13]), f2bf_r(a16[14]), f2bf_r(a16[15])};
    *(bf16x8*)&As[row * 136 + seg * 16] = w0;
    *(bf16x8*)&As[row * 136 + seg * 16 + 8] = w1;
  }
  __syncthreads();
  f32x4 acc[4];
  f32x4 zz = {0.f, 0.f, 0.f, 0.f};
  acc[0] = zz; acc[1] = zz; acc[2] = zz; acc[3] = zz;
  mfma_accum(As, W, rt, ch, quad, r16, acc);
#pragma unroll
  for (int nt = 0; nt < 4; ++nt) {
    int col = ch * 64 + nt * 16 + r16;
    float bs = bias[col];
#pragma unroll
    for (int g = 0; g < 4; ++g) {
      int lr = rt * 16 + quad * 4 + g;
      Cs[lr * 132 + col] = acc[nt][g] + bs + Rres[(size_t)(m0 + lr) * D + col];
    }
  }
  __syncthreads();
  {
    int row = t >> 3, seg = t & 7;
    float xv[16];
#pragma unroll
    for (int q = 0; q < 4; ++q) {
      f32x4 v = *(f32x4*)&Cs[row * 132 + seg * 16 + q * 4];
      xv[q * 4] = v[0]; xv[q * 4 + 1] = v[1]; xv[q * 4 + 2] = v[2]; xv[q * 4 + 3] = v[3];
    }
    float s = 0.f, sq = 0.f;
#pragma unroll
    for (int k = 0; k < 16; ++k) { s += xv[k]; sq += xv[k] * xv[k]; }
#pragma unroll
    for (int mask = 1; mask < 8; mask <<= 1) { s += __shfl_xor(s, mask); sq += __shfl_xor(sq, mask); }
    float mu = s * (1.f / 128.f);
    float var = fmaxf(sq * (1.f / 128.f) - mu * mu, 0.f);
    float rs = rsqrtf(var + 1e-5f);
    float yv[16], nn = 0.f;
#pragma unroll
    for (int q = 0; q < 4; ++q) {
      float4 gg = ld4(&ln_g[seg * 16 + q * 4]);
      float4 bb = ld4(&ln_b[seg * 16 + q * 4]);
      float y0 = (xv[q * 4] - mu) * rs * gg.x + bb.x;
      float y1 = (xv[q * 4 + 1] - mu) * rs * gg.y + bb.y;
      float y2 = (xv[q * 4 + 2] - mu) * rs * gg.z + bb.z;
      float y3 = (xv[q * 4 + 3] - mu) * rs * gg.w + bb.w;
      yv[q * 4] = y0; yv[q * 4 + 1] = y1; yv[q * 4 + 2] = y2; yv[q * 4 + 3] = y3;
      nn += y0 * y0 + y1 * y1 + y2 * y2 + y3 * y3;
    }
#pragma unroll
    for (int mask = 1; mask < 8; mask <<= 1) nn += __shfl_xor(nn, mask);
    float inv = 1.f / fmaxf(sqrtf(nn), 1e-12f);
#pragma unroll
    for (int q = 0; q < 4; ++q) {
      float4 ov = {yv[q * 4] * inv, yv[q * 4 + 1] * inv, yv[q * 4 + 2] * inv, yv[q * 4 + 3] * inv};
      *(float4*)&emb[(size_t)(m0 + row) * D + seg * 16 + q * 4] = ov;
    }
  }
}

// ---------------- MLP GEMM fused with sigmoid ----------------
__global__ __launch_bounds__(256) void gemm_mlp_kernel(
    const float* __restrict__ emb, const short* __restrict__ W,
    const float* __restrict__ w2, float* __restrict__ pbuf) {
  __shared__ short As[32 * 136];
  __shared__ float part[32][2];
  const int t = threadIdx.x;
  const int m0 = blockIdx.x * 32;
  const int w = t >> 6, lane = t & 63, quad = lane >> 4, r16 = lane & 15;
  const int rt = w & 1, ch = w >> 1;
  stage_A_f32(emb, m0, As);
  __syncthreads();
  f32x4 acc[4];
  f32x4 zz = {0.f, 0.f, 0.f, 0.f};
  acc[0] = zz; acc[1] = zz; acc[2] = zz; acc[3] = zz;
  mfma_accum(As, W, rt, ch, quad, r16, acc);
  float pg[4] = {};
#pragma unroll
  for (int nt = 0; nt < 4; ++nt) {
    float wv = w2[ch * 64 + nt * 16 + r16];
#pragma unroll
    for (int g = 0; g < 4; ++g) pg[g] += fmaxf(acc[nt][g], 0.f) * wv;
  }
#pragma unroll
  for (int mask = 1; mask < 16; mask <<= 1)
#pragma unroll
    for (int g = 0; g < 4; ++g) pg[g] += __shfl_xor(pg[g], mask);
  if (r16 == 0) {
#pragma unroll
    for (int g = 0; g < 4; ++g) part[rt * 16 + quad * 4 + g][ch] = pg[g];
  }
  __syncthreads();
  if (t < 32) {
    float sv = part[t][0] + part[t][1];
    pbuf[m0 + t] = 1.f / (1.f + __expf(-sv));
  }
}

// ---------------- edge prediction ----------------
__global__ void pred_kernel(const float* __restrict__ p, const int* __restrict__ eli,
                            float* __restrict__ out, int K) {
  int i = blockIdx.x * blockDim.x + threadIdx.x;
  if (i < K) out[i] = p[eli[i]] * p[eli[K + i]];
}

extern "C" void kernel_launch(void* const* d_in, const int* in_sizes, int n_in,
                              void* d_out, int out_size, void* d_ws, size_t ws_size,
                              hipStream_t stream) {
  const float* x       = (const float*)d_in[0];
  const float* seq     = (const float*)d_in[1];
  const int* src       = (const int*)d_in[2];
  const int* dst       = (const int*)d_in[3];
  const int* eli       = (const int*)d_in[4];
  const float* skip_w0 = (const float*)d_in[5];
  const float* skip_b0 = (const float*)d_in[6];
  const float* msg_w0  = (const float*)d_in[7];
  const float* msg_b0  = (const float*)d_in[8];
  const float* skip_w1 = (const float*)d_in[9];
  const float* skip_b1 = (const float*)d_in[10];
  const float* msg_w1  = (const float*)d_in[11];
  const float* msg_b1  = (const float*)d_in[12];
  const float* ipw     = (const float*)d_in[13];
  const float* ipb     = (const float*)d_in[14];
  const float* opw     = (const float*)d_in[15];
  const float* opb     = (const float*)d_in[16];
  const float* ln_g    = (const float*)d_in[17];
  const float* ln_b    = (const float*)d_in[18];
  const float* w1      = (const float*)d_in[19];
  const float* w2      = (const float*)d_in[20];

  const int N  = in_sizes[0] / D;   // 8192
  const int S  = in_sizes[1] / D;   // 2048
  const int E  = in_sizes[2];       // 524288
  const int Kp = in_sizes[4] / 2;   // 100000

  float* ws    = (float*)d_ws;
  float* B2    = ws;                                   // N*D
  float* Osp   = B2 + (size_t)N * D;                   // SPLITS*N*D
  short* xbf   = (short*)(Osp + (size_t)SPLITS * N * D);
  short* Abf   = xbf + (size_t)N * D;
  short* B1bf  = Abf + (size_t)N * D;
  short* Qbf   = B1bf + (size_t)N * D;
  short* Kbf   = Qbf + (size_t)N * D;
  short* Vt    = Kbf + (size_t)S * D;
  short* Wbf   = Vt + (size_t)D * S;                   // 9*16384
  float* qn    = (float*)(Wbf + 9 * 16384);            // 4N
  float* lbuf  = qn + 4 * (size_t)N;                   // 4*SPLITS*N
  float* dinv  = lbuf + 4 * (size_t)SPLITS * N;
  float* pbuf  = dinv + N;
  int*   MkhI  = (int*)(pbuf + N);                     // 4
  int*   bar   = MkhI + 4;                             // 1
  int*   bsum  = bar + 1;                              // HB
  int* row_ptr = bsum + HB;                            // N+1
  int* csr_src = row_ptr + (N + 1);                    // E
  int* histd   = csr_src + E;                          // HB*8192
  int* hists   = histd + HB * 8192;                    // HB*8192
  int* base_arr= hists + HB * 8192;                    // HB*8192

  float* pred_out = (float*)d_out;
  float* emb_out  = pred_out + Kp;

  const short* w_skip0 = Wbf + 0 * 16384;
  const short* w_msg0  = Wbf + 1 * 16384;
  const short* w_skip1 = Wbf + 2 * 16384;
  const short* w_msg1  = Wbf + 3 * 16384;
  const short* w_q     = Wbf + 4 * 16384;
  const short* w_k     = Wbf + 5 * 16384;
  const short* w_v     = Wbf + 6 * 16384;
  const short* w_op    = Wbf + 7 * 16384;
  const short* w_m1    = Wbf + 8 * 16384;

  WSrc wsrc;
  wsrc.p[0] = skip_w0; wsrc.p[1] = msg_w0; wsrc.p[2] = skip_w1; wsrc.p[3] = msg_w1;
  wsrc.p[4] = ipw; wsrc.p[5] = ipw + D * D; wsrc.p[6] = ipw + 2 * D * D;
  wsrc.p[7] = opw; wsrc.p[8] = w1;
  prep0_kernel<<<144 + (N * D / 1024), 256, 0, stream>>>(wsrc, (short*)Wbf, x, xbf, bar, MkhI);

  // single-dispatch CSR build
  csr_kernel<<<HB, 256, 0, stream>>>(src, dst, histd, hists, base_arr, csr_src,
                                     dinv, row_ptr, bsum, bar, E, N);

  // GCN layers
  agg_kernel<<<N, 128, 0, stream>>>(xbf, dinv, row_ptr, csr_src, Abf);
  gemm_gcn_kernel<<<N / 32, 256, 0, stream>>>(Abf, w_msg0, msg_b0, xbf, w_skip0, skip_b0, B1bf, nullptr);
  agg_kernel<<<N, 128, 0, stream>>>(B1bf, dinv, row_ptr, csr_src, Abf);
  gemm_gcn_kernel<<<N / 32, 256, 0, stream>>>(Abf, w_msg1, msg_b1, B1bf, w_skip1, skip_b1, nullptr, B2);

  // fused QKV + attention prep
  qkv_kernel<<<N / 32 + 2 * (S / 32), 256, 0, stream>>>(
      B2, seq, w_q, w_k, w_v, ipb, Qbf, qn, Kbf, MkhI, Vt, N, S);

  // attention: split-S=8, plain stores, merge fused into out_proj GEMM
  dim3 fgrid(N / 32, 4, SPLITS);
  flash_kernel<<<fgrid, 64, 0, stream>>>(Qbf, Kbf, Vt, qn, MkhI, Osp, lbuf, N, S);
  gemm_op_kernel<<<N / 32, 256, 0, stream>>>(Osp, lbuf, w_op, opb, B2, ln_g, ln_b, emb_out, N);

  // MLP (+sigmoid) and prediction
  gemm_mlp_kernel<<<N / 32, 256, 0, stream>>>(emb_out, w_m1, w2, pbuf);
  pred_kernel<<<(Kp + 255) / 256, 256, 0, stream>>>(pbuf, eli, pred_out, Kp);
}

// Round 8
// 285.447 us; speedup vs baseline: 1.2510x; 1.2510x over previous
//
#include <hip/hip_runtime.h>
#include <math.h>

#define D 128
#define HB 128     // histogram blocks
#define FA_PS 88   // flash P stride (shorts)
#define SPLITS 8

typedef short bf16x4 __attribute__((ext_vector_type(4)));
typedef short bf16x8 __attribute__((ext_vector_type(8)));
typedef float f32x4 __attribute__((ext_vector_type(4)));

__device__ __forceinline__ float4 ld4(const float* p) { return *(const float4*)p; }

__device__ __forceinline__ short f2bf_r(float f) {
  return (short)((__float_as_uint(f) + 0x8000u) >> 16);
}
__device__ __forceinline__ float bf2f(short s) {
  return __uint_as_float(((unsigned)(unsigned short)s) << 16);
}
__device__ __forceinline__ unsigned pack_bf2(float a, float b) {
  unsigned ua = __float_as_uint(a) + 0x8000u;
  unsigned ub = __float_as_uint(b) + 0x8000u;
  return __builtin_amdgcn_perm(ub, ua, 0x07060302);
}

// ---------------- prep0: weights + x -> bf16; zero MkhI ----------------
struct WSrc { const float* p[9]; };
__global__ __launch_bounds__(256) void prep0_kernel(WSrc ws, short* __restrict__ Wbf,
                                                    const float* __restrict__ x,
                                                    short* __restrict__ xbf,
                                                    int* __restrict__ MkhI) {
  int b = blockIdx.x, t = threadIdx.x;
  if (b == 0 && t < 4) MkhI[t] = 0;
  if (b < 144) {
    int m = b >> 4, blk = b & 15;
    int i = (blk * 256 + t) * 4;
    float4 v = ld4(ws.p[m] + i);
    bf16x4 o = {f2bf_r(v.x), f2bf_r(v.y), f2bf_r(v.z), f2bf_r(v.w)};
    *(bf16x4*)&Wbf[m * 16384 + i] = o;
  } else {
    int i = ((b - 144) * 256 + t) * 4;
    float4 v = ld4(x + i);
    bf16x4 o = {f2bf_r(v.x), f2bf_r(v.y), f2bf_r(v.z), f2bf_r(v.w)};
    *(bf16x4*)&xbf[i] = o;
  }
}

// ---------------- CSR build, atomic-free (LDS-privatized histograms), 5 kernels ----------------
__global__ __launch_bounds__(256) void hist_kernel(
    const int* __restrict__ src, const int* __restrict__ dst,
    int* __restrict__ histd, int* __restrict__ hists, int E) {
  __shared__ int hd[8192];
  __shared__ int hs[8192];
  int t = threadIdx.x;
  for (int i = t; i < 8192; i += 256) { hd[i] = 0; hs[i] = 0; }
  __syncthreads();
  int per = E / HB;
  int b0 = blockIdx.x * per;
  for (int j = 0; j < per; j += 256) {
    int i = b0 + j + t;
    atomicAdd(&hd[dst[i]], 1);
    atomicAdd(&hs[src[i]], 1);
  }
  __syncthreads();
  for (int i = t; i < 8192; i += 256) {
    histd[blockIdx.x * 8192 + i] = hd[i];
    hists[blockIdx.x * 8192 + i] = hs[i];
  }
}

__global__ __launch_bounds__(256) void colsum_kernel(
    const int* __restrict__ histd, const int* __restrict__ hists,
    int* __restrict__ deg, float* __restrict__ dinv) {
  int v = blockIdx.x * 256 + threadIdx.x;
  int sd = 0, ss = 0;
  for (int b = 0; b < HB; ++b) { sd += histd[b * 8192 + v]; ss += hists[b * 8192 + v]; }
  deg[v] = sd;
  dinv[v] = ss > 0 ? rsqrtf((float)ss) : 0.f;
}

__global__ __launch_bounds__(1024) void scan8k_kernel(
    const int* __restrict__ deg, int* __restrict__ row_ptr, int N) {
  __shared__ int wtot[16];
  int t = threadIdx.x;
  int lane = t & 63, wv = t >> 6;
  int v0 = t * 8;
  int x[8]; int s = 0;
#pragma unroll
  for (int j = 0; j < 8; ++j) { x[j] = s; s += deg[v0 + j]; }
  int incl = s;
  for (int off = 1; off < 64; off <<= 1) {
    int y = __shfl_up(incl, off);
    if (lane >= off) incl += y;
  }
  if (lane == 63) wtot[wv] = incl;
  __syncthreads();
  if (t == 0) { int run = 0; for (int i = 0; i < 16; ++i) { int v = wtot[i]; wtot[i] = run; run += v; } }
  __syncthreads();
  int base = wtot[wv] + (incl - s);
#pragma unroll
  for (int j = 0; j < 8; ++j) row_ptr[v0 + j] = base + x[j];
  if (t == 1023) row_ptr[N] = base + s;
}

__global__ __launch_bounds__(256) void basegen_kernel(
    const int* __restrict__ histd, const int* __restrict__ row_ptr,
    int* __restrict__ base_arr) {
  int v = blockIdx.x * 256 + threadIdx.x;
  int run = row_ptr[v];
  for (int b = 0; b < HB; ++b) { base_arr[b * 8192 + v] = run; run += histd[b * 8192 + v]; }
}

__global__ __launch_bounds__(256) void scatter2_kernel(
    const int* __restrict__ src, const int* __restrict__ dst,
    const int* __restrict__ base_arr, int* __restrict__ csr_src, int E) {
  __shared__ int lh[8192];
  int t = threadIdx.x;
  for (int i = t; i < 8192; i += 256) lh[i] = 0;
  __syncthreads();
  int per = E / HB;
  int b0 = blockIdx.x * per;
  const int* __restrict__ bb = &base_arr[blockIdx.x * 8192];
  for (int j = 0; j < per; j += 256) {
    int i = b0 + j + t;
    int v = dst[i];
    int r = atomicAdd(&lh[v], 1);
    csr_src[bb[v] + r] = src[i];
  }
}

// ---------------- GCN aggregation: bf16 gather, 4 independent edge streams ----------------
__global__ __launch_bounds__(128) void agg_kernel(
    const short* __restrict__ fbf, const float* __restrict__ dinv,
    const int* __restrict__ row_ptr, const int* __restrict__ csr_src,
    short* __restrict__ outbf) {
  __shared__ int idx[128];
  __shared__ float dv[128];
  __shared__ float red[8][128];
  int n = blockIdx.x, t = threadIdx.x;
  int grp = t >> 4, l16 = t & 15;
  int beg = row_ptr[n], end = row_ptr[n + 1];
  float a0[8] = {}, a1[8] = {}, a2[8] = {}, a3[8] = {};
  for (int c = beg; c < end; c += 128) {
    int j = c + t;
    if (j < end) { int s = csr_src[j]; idx[t] = s; dv[t] = dinv[s]; }
    __syncthreads();
    int cnt = min(128, end - c);
    int e = grp;
    for (; e + 24 < cnt; e += 32) {
      bf16x8 w0 = *(const bf16x8*)&fbf[(size_t)idx[e] * D + l16 * 8];
      bf16x8 w1 = *(const bf16x8*)&fbf[(size_t)idx[e + 8] * D + l16 * 8];
      bf16x8 w2 = *(const bf16x8*)&fbf[(size_t)idx[e + 16] * D + l16 * 8];
      bf16x8 w3 = *(const bf16x8*)&fbf[(size_t)idx[e + 24] * D + l16 * 8];
      float wt0 = dv[e], wt1 = dv[e + 8], wt2 = dv[e + 16], wt3 = dv[e + 24];
#pragma unroll
      for (int k = 0; k < 8; ++k) {
        a0[k] += bf2f(w0[k]) * wt0;
        a1[k] += bf2f(w1[k]) * wt1;
        a2[k] += bf2f(w2[k]) * wt2;
        a3[k] += bf2f(w3[k]) * wt3;
      }
    }
    for (; e < cnt; e += 8) {
      bf16x8 w0 = *(const bf16x8*)&fbf[(size_t)idx[e] * D + l16 * 8];
      float wt0 = dv[e];
#pragma unroll
      for (int k = 0; k < 8; ++k) a0[k] += bf2f(w0[k]) * wt0;
    }
    __syncthreads();
  }
#pragma unroll
  for (int k = 0; k < 8; ++k) a0[k] += a1[k] + a2[k] + a3[k];
  *(float4*)&red[grp][l16 * 8] = *(float4*)&a0[0];
  *(float4*)&red[grp][l16 * 8 + 4] = *(float4*)&a0[4];
  __syncthreads();
  if (t < 32) {
    int d0 = t * 4;
    float o[4] = {};
#pragma unroll
    for (int g = 0; g < 8; ++g) {
      o[0] += red[g][d0]; o[1] += red[g][d0 + 1];
      o[2] += red[g][d0 + 2]; o[3] += red[g][d0 + 3];
    }
    float w = dinv[n];
    bf16x4 ov = {f2bf_r(o[0] * w), f2bf_r(o[1] * w), f2bf_r(o[2] * w), f2bf_r(o[3] * w)};
    *(bf16x4*)&outbf[(size_t)n * D + d0] = ov;
  }
}

// ---------------- MFMA helpers ----------------
__device__ __forceinline__ void mfma_accum(const short* As, const short* __restrict__ W,
                                           int rt, int ch, int quad, int r16, f32x4* acc) {
#pragma unroll
  for (int ks = 0; ks < 4; ++ks) {
    bf16x8 af = *(bf16x8*)&As[(rt * 16 + r16) * 136 + ks * 32 + quad * 8];
#pragma unroll
    for (int nt = 0; nt < 4; ++nt) {
      bf16x8 bw = *(const bf16x8*)&W[(size_t)(ch * 64 + nt * 16 + r16) * D + ks * 32 + quad * 8];
      acc[nt] = __builtin_amdgcn_mfma_f32_16x16x32_bf16(af, bw, acc[nt], 0, 0, 0);
    }
  }
}

__device__ __forceinline__ void stage_A_f32(const float* __restrict__ A, int m0, short* As) {
  int row = threadIdx.x >> 3, seg = threadIdx.x & 7;
  const float* ap = &A[(size_t)(m0 + row) * D + seg * 16];
  float4 v0 = ld4(ap), v1 = ld4(ap + 4), v2 = ld4(ap + 8), v3 = ld4(ap + 12);
  bf16x8 w0 = {f2bf_r(v0.x), f2bf_r(v0.y), f2bf_r(v0.z), f2bf_r(v0.w),
               f2bf_r(v1.x), f2bf_r(v1.y), f2bf_r(v1.z), f2bf_r(v1.w)};
  bf16x8 w1 = {f2bf_r(v2.x), f2bf_r(v2.y), f2bf_r(v2.z), f2bf_r(v2.w),
               f2bf_r(v3.x), f2bf_r(v3.y), f2bf_r(v3.z), f2bf_r(v3.w)};
  *(bf16x8*)&As[row * 136 + seg * 16] = w0;
  *(bf16x8*)&As[row * 136 + seg * 16 + 8] = w1;
}

__device__ __forceinline__ void stage_A_bf16(const short* __restrict__ A, int m0, short* As) {
  int row = threadIdx.x >> 3, seg = threadIdx.x & 7;
  const short* ap = &A[(size_t)(m0 + row) * D + seg * 16];
  bf16x8 a0 = *(const bf16x8*)ap;
  bf16x8 a1 = *(const bf16x8*)(ap + 8);
  *(bf16x8*)&As[row * 136 + seg * 16] = a0;
  *(bf16x8*)&As[row * 136 + seg * 16 + 8] = a1;
}

// ---------------- GCN dual GEMM ----------------
__global__ __launch_bounds__(256) void gemm_gcn_kernel(
    const short* __restrict__ A1, const short* __restrict__ W1, const float* __restrict__ b1,
    const short* __restrict__ A2, const short* __restrict__ W2, const float* __restrict__ b2,
    short* __restrict__ Cbf, float* __restrict__ Cf) {
  __shared__ short As[32 * 136];
  const int t = threadIdx.x;
  const int m0 = blockIdx.x * 32;
  const int w = t >> 6, lane = t & 63, quad = lane >> 4, r16 = lane & 15;
  const int rt = w & 1, ch = w >> 1;
  f32x4 acc[4];
  f32x4 zz = {0.f, 0.f, 0.f, 0.f};
  acc[0] = zz; acc[1] = zz; acc[2] = zz; acc[3] = zz;
  stage_A_bf16(A1, m0, As);
  __syncthreads();
  mfma_accum(As, W1, rt, ch, quad, r16, acc);
  __syncthreads();
  stage_A_bf16(A2, m0, As);
  __syncthreads();
  mfma_accum(As, W2, rt, ch, quad, r16, acc);
#pragma unroll
  for (int nt = 0; nt < 4; ++nt) {
    int col = ch * 64 + nt * 16 + r16;
    float bias = b1[col] + b2[col];
#pragma unroll
    for (int g = 0; g < 4; ++g) {
      int row = m0 + rt * 16 + quad * 4 + g;
      float v = acc[nt][g] + bias;
      if (Cbf) Cbf[(size_t)row * D + col] = f2bf_r(v);
      if (Cf) Cf[(size_t)row * D + col] = v;
    }
  }
}

// ---------------- fused QKV projections with prep epilogues ----------------
__global__ __launch_bounds__(256) void qkv_kernel(
    const float* __restrict__ B2, const float* __restrict__ seq,
    const short* __restrict__ Wq, const short* __restrict__ Wk, const short* __restrict__ Wv,
    const float* __restrict__ ipb,
    short* __restrict__ Qbf, float* __restrict__ qn,
    short* __restrict__ Kbf, int* __restrict__ MkhI,
    short* __restrict__ Vt, int N, int S) {
  __shared__ short As[32 * 136];
  __shared__ int lmax[4];
  const int t = threadIdx.x;
  const int b = blockIdx.x;
  const int w = t >> 6, lane = t & 63, quad = lane >> 4, r16 = lane & 15;
  const int rt = w & 1, ch = w >> 1;
  if (t < 4) lmax[t] = 0;
  f32x4 acc[4];
  f32x4 zz = {0.f, 0.f, 0.f, 0.f};
  acc[0] = zz; acc[1] = zz; acc[2] = zz; acc[3] = zz;
  const float SC = 0.25503473f;   // (1/sqrt(32)) * log2(e)

  if (b < 256) {
    int m0 = b * 32;
    stage_A_f32(B2, m0, As);
    __syncthreads();
    mfma_accum(As, Wq, rt, ch, quad, r16, acc);
    float pq[4][2] = {};
#pragma unroll
    for (int nt = 0; nt < 4; ++nt) {
      int col = ch * 64 + nt * 16 + r16;
      float bias = ipb[col];
      int p = nt >> 1;
#pragma unroll
      for (int g = 0; g < 4; ++g) {
        int row = m0 + rt * 16 + quad * 4 + g;
        float vs = (acc[nt][g] + bias) * SC;
        Qbf[(size_t)row * D + col] = f2bf_r(vs);
        pq[g][p] += vs * vs;
      }
    }
#pragma unroll
    for (int mask = 1; mask < 16; mask <<= 1)
#pragma unroll
      for (int g = 0; g < 4; ++g) {
        pq[g][0] += __shfl_xor(pq[g][0], mask);
        pq[g][1] += __shfl_xor(pq[g][1], mask);
      }
    if (r16 == 0) {
#pragma unroll
      for (int g = 0; g < 4; ++g) {
        int row = m0 + rt * 16 + quad * 4 + g;
        qn[(ch * 2 + 0) * N + row] = sqrtf(pq[g][0]);
        qn[(ch * 2 + 1) * N + row] = sqrtf(pq[g][1]);
      }
    }
  } else if (b < 320) {
    int m0 = (b - 256) * 32;
    stage_A_f32(seq, m0, As);
    __syncthreads();
    mfma_accum(As, Wk, rt, ch, quad, r16, acc);
    float pk[4][2] = {};
#pragma unroll
    for (int nt = 0; nt < 4; ++nt) {
      int col = ch * 64 + nt * 16 + r16;
      float bias = ipb[128 + col];
      int p = nt >> 1;
#pragma unroll
      for (int g = 0; g < 4; ++g) {
        int key = m0 + rt * 16 + quad * 4 + g;
        float v = acc[nt][g] + bias;
        Kbf[(size_t)key * D + col] = f2bf_r(v);
        pk[g][p] += v * v;
      }
    }
#pragma unroll
    for (int mask = 1; mask < 16; mask <<= 1)
#pragma unroll
      for (int g = 0; g < 4; ++g) {
        pk[g][0] += __shfl_xor(pk[g][0], mask);
        pk[g][1] += __shfl_xor(pk[g][1], mask);
      }
    if (r16 == 0) {
#pragma unroll
      for (int g = 0; g < 4; ++g) {
        atomicMax(&lmax[ch * 2 + 0], __float_as_int(pk[g][0]));
        atomicMax(&lmax[ch * 2 + 1], __float_as_int(pk[g][1]));
      }
    }
    __syncthreads();
    if (t < 4) atomicMax(&MkhI[t], lmax[t]);
  } else {
    int m0 = (b - 320) * 32;
    stage_A_f32(seq, m0, As);
    __syncthreads();
    mfma_accum(As, Wv, rt, ch, quad, r16, acc);
#pragma unroll
    for (int nt = 0; nt < 4; ++nt) {
      int dim = ch * 64 + nt * 16 + r16;
      float bias = ipb[256 + dim];
#pragma unroll
      for (int g = 0; g < 4; ++g) {
        int s = m0 + rt * 16 + quad * 4 + g;
        int local = s & 63;
        int kp = (local & 15) * 4 + (local >> 4);     // key' permutation
        int gcol = (s & ~63) + kp;
        Vt[(size_t)dim * S + gcol] = f2bf_r(acc[nt][g] + bias);
      }
    }
  }
}

// ---------------- MFMA flash attention: fixed-shift (log2), split-S=8, permuted P ----------------
__global__ __launch_bounds__(64, 8) void flash_kernel(
    const short* __restrict__ Qbf, const short* __restrict__ Kbf, const short* __restrict__ Vt,
    const float* __restrict__ qn, const int* __restrict__ MkhI,
    float* __restrict__ Osp, float* __restrict__ lbuf, int N, int S) {
  __shared__ short Ps[32 * FA_PS];
  const int lane = threadIdx.x;
  const int quad = lane >> 4, r16 = lane & 15;
  const int n0 = blockIdx.x * 32;
  const int h = blockIdx.y;
  const int sp = blockIdx.z;
  float* O = Osp + (size_t)sp * N * D;

  bf16x8 aq[2];
  aq[0] = *(const bf16x8*)&Qbf[(size_t)(n0 + r16) * D + h * 32 + quad * 8];
  aq[1] = *(const bf16x8*)&Qbf[(size_t)(n0 + 16 + r16) * D + h * 32 + quad * 8];

  float sqm = sqrtf(fmaxf(__int_as_float(MkhI[h]), 0.f));
  float msh[2][4];
#pragma unroll
  for (int rt = 0; rt < 2; ++rt)
#pragma unroll
    for (int g = 0; g < 4; ++g)
      msh[rt][g] = fminf(qn[h * N + n0 + rt * 16 + quad * 4 + g] * sqm, 57.7f);

  f32x4 o[2][2], lac[2];
  f32x4 zz = {0.f, 0.f, 0.f, 0.f};
  o[0][0] = zz; o[0][1] = zz; o[1][0] = zz; o[1][1] = zz;
  lac[0] = zz; lac[1] = zz;
  bf16x8 ones = {(short)0x3F80, (short)0x3F80, (short)0x3F80, (short)0x3F80,
                 (short)0x3F80, (short)0x3F80, (short)0x3F80, (short)0x3F80};

  const int span = S / SPLITS;
  const int c0 = sp * span;
  for (int c = c0; c < c0 + span; c += 64) {
    f32x4 s[2][4];
#pragma unroll
    for (int kt = 0; kt < 4; ++kt) {
      bf16x8 bk = *(const bf16x8*)&Kbf[(size_t)(c + kt * 16 + r16) * D + h * 32 + quad * 8];
      f32x4 z = {0.f, 0.f, 0.f, 0.f};
      s[0][kt] = __builtin_amdgcn_mfma_f32_16x16x32_bf16(aq[0], bk, z, 0, 0, 0);
      s[1][kt] = __builtin_amdgcn_mfma_f32_16x16x32_bf16(aq[1], bk, z, 0, 0, 0);
    }
#pragma unroll
    for (int rt = 0; rt < 2; ++rt)
#pragma unroll
      for (int g = 0; g < 4; ++g) {
        float m = msh[rt][g];
        float p0 = exp2f(s[rt][0][g] - m);
        float p1 = exp2f(s[rt][1][g] - m);
        float p2 = exp2f(s[rt][2][g] - m);
        float p3 = exp2f(s[rt][3][g] - m);
        uint2 uv = {pack_bf2(p0, p1), pack_bf2(p2, p3)};
        *(uint2*)&Ps[(rt * 16 + quad * 4 + g) * FA_PS + r16 * 4] = uv;
      }
    bf16x8 bv[2][2];
#pragma unroll
    for (int kc = 0; kc < 2; ++kc)
#pragma unroll
      for (int nt = 0; nt < 2; ++nt)
        bv[kc][nt] = *(const bf16x8*)&Vt[(size_t)(h * 32 + nt * 16 + r16) * S + c + kc * 32 + quad * 8];
#pragma unroll
    for (int rt = 0; rt < 2; ++rt)
#pragma unroll
      for (int kc = 0; kc < 2; ++kc) {
        bf16x8 ap = *(bf16x8*)&Ps[(rt * 16 + r16) * FA_PS + kc * 32 + quad * 8];
        lac[rt] = __builtin_amdgcn_mfma_f32_16x16x32_bf16(ap, ones, lac[rt], 0, 0, 0);
#pragma unroll
        for (int nt = 0; nt < 2; ++nt)
          o[rt][nt] = __builtin_amdgcn_mfma_f32_16x16x32_bf16(ap, bv[kc][nt], o[rt][nt], 0, 0, 0);
      }
  }
#pragma unroll
  for (int rt = 0; rt < 2; ++rt)
#pragma unroll
    for (int g = 0; g < 4; ++g) {
      int row = n0 + rt * 16 + quad * 4 + g;
#pragma unroll
      for (int nt = 0; nt < 2; ++nt)
        O[(size_t)row * D + h * 32 + nt * 16 + r16] = o[rt][nt][g];
      if (r16 == 0) lbuf[(sp * 4 + h) * N + row] = lac[rt][g];
    }
}

// ---------------- out_proj GEMM: fused split-merge + residual + LN + L2 ----------------
__global__ __launch_bounds__(256) void gemm_op_kernel(
    const float* __restrict__ Osp, const float* __restrict__ lbuf,
    const short* __restrict__ W, const float* __restrict__ bias,
    const float* __restrict__ Rres, const float* __restrict__ ln_g,
    const float* __restrict__ ln_b, float* __restrict__ emb, int N) {
  __shared__ short As[32 * 136];
  __shared__ float Cs[32 * 132];
  const int t = threadIdx.x;
  const int m0 = blockIdx.x * 32;
  const int w = t >> 6, lane = t & 63, quad = lane >> 4, r16 = lane & 15;
  const int rt = w & 1, ch = w >> 1;
  {
    int row = t >> 3, seg = t & 7;
    int grow = m0 + row;
    int hh = seg >> 1;
    float l = 0.f;
#pragma unroll
    for (int s = 0; s < SPLITS; ++s) l += lbuf[(s * 4 + hh) * N + grow];
    float inv = 1.f / l;
    const float* p = &Osp[(size_t)grow * D + seg * 16];
    size_t st = (size_t)N * D;
    float a16[16] = {};
#pragma unroll
    for (int s = 0; s < SPLITS; ++s) {
#pragma unroll
      for (int q = 0; q < 4; ++q) {
        float4 a = ld4(p + s * st + q * 4);
        a16[q * 4 + 0] += a.x; a16[q * 4 + 1] += a.y;
        a16[q * 4 + 2] += a.z; a16[q * 4 + 3] += a.w;
      }
    }
#pragma unroll
    for (int k = 0; k < 16; ++k) a16[k] *= inv;
    bf16x8 w0 = {f2bf_r(a16[0]), f2bf_r(a16[1]), f2bf_r(a16[2]), f2bf_r(a16[3]),
                 f2bf_r(a16[4]), f2bf_r(a16[5]), f2bf_r(a16[6]), f2bf_r(a16[7])};
    bf16x8 w1 = {f2bf_r(a16[8]), f2bf_r(a16[9]), f2bf_r(a16[10]), f2bf_r(a16[11]),
                 f2bf_r(a16[12]), f2bf_r(a16[13]), f2bf_r(a16[14]), f2bf_r(a16[15])};
    *(bf16x8*)&As[row * 136 + seg * 16] = w0;
    *(bf16x8*)&As[row * 136 + seg * 16 + 8] = w1;
  }
  __syncthreads();
  f32x4 acc[4];
  f32x4 zz = {0.f, 0.f, 0.f, 0.f};
  acc[0] = zz; acc[1] = zz; acc[2] = zz; acc[3] = zz;
  mfma_accum(As, W, rt, ch, quad, r16, acc);
#pragma unroll
  for (int nt = 0; nt < 4; ++nt) {
    int col = ch * 64 + nt * 16 + r16;
    float bs = bias[col];
#pragma unroll
    for (int g = 0; g < 4; ++g) {
      int lr = rt * 16 + quad * 4 + g;
      Cs[lr * 132 + col] = acc[nt][g] + bs + Rres[(size_t)(m0 + lr) * D + col];
    }
  }
  __syncthreads();
  {
    int row = t >> 3, seg = t & 7;
    float xv[16];
#pragma unroll
    for (int q = 0; q < 4; ++q) {
      f32x4 v = *(f32x4*)&Cs[row * 132 + seg * 16 + q * 4];
      xv[q * 4] = v[0]; xv[q * 4 + 1] = v[1]; xv[q * 4 + 2] = v[2]; xv[q * 4 + 3] = v[3];
    }
    float s = 0.f, sq = 0.f;
#pragma unroll
    for (int k = 0; k < 16; ++k) { s += xv[k]; sq += xv[k] * xv[k]; }
#pragma unroll
    for (int mask = 1; mask < 8; mask <<= 1) { s += __shfl_xor(s, mask); sq += __shfl_xor(sq, mask); }
    float mu = s * (1.f / 128.f);
    float var = fmaxf(sq * (1.f / 128.f) - mu * mu, 0.f);
    float rs = rsqrtf(var + 1e-5f);
    float yv[16], nn = 0.f;
#pragma unroll
    for (int q = 0; q < 4; ++q) {
      float4 gg = ld4(&ln_g[seg * 16 + q * 4]);
      float4 bb = ld4(&ln_b[seg * 16 + q * 4]);
      float y0 = (xv[q * 4] - mu) * rs * gg.x + bb.x;
      float y1 = (xv[q * 4 + 1] - mu) * rs * gg.y + bb.y;
      float y2 = (xv[q * 4 + 2] - mu) * rs * gg.z + bb.z;
      float y3 = (xv[q * 4 + 3] - mu) * rs * gg.w + bb.w;
      yv[q * 4] = y0; yv[q * 4 + 1] = y1; yv[q * 4 + 2] = y2; yv[q * 4 + 3] = y3;
      nn += y0 * y0 + y1 * y1 + y2 * y2 + y3 * y3;
    }
#pragma unroll
    for (int mask = 1; mask < 8; mask <<= 1) nn += __shfl_xor(nn, mask);
    float inv = 1.f / fmaxf(sqrtf(nn), 1e-12f);
#pragma unroll
    for (int q = 0; q < 4; ++q) {
      float4 ov = {yv[q * 4] * inv, yv[q * 4 + 1] * inv, yv[q * 4 + 2] * inv, yv[q * 4 + 3] * inv};
      *(float4*)&emb[(size_t)(m0 + row) * D + seg * 16 + q * 4] = ov;
    }
  }
}

// ---------------- MLP GEMM fused with sigmoid ----------------
__global__ __launch_bounds__(256) void gemm_mlp_kernel(
    const float* __restrict__ emb, const short* __restrict__ W,
    const float* __restrict__ w2, float* __restrict__ pbuf) {
  __shared__ short As[32 * 136];
  __shared__ float part[32][2];
  const int t = threadIdx.x;
  const int m0 = blockIdx.x * 32;
  const int w = t >> 6, lane = t & 63, quad = lane >> 4, r16 = lane & 15;
  const int rt = w & 1, ch = w >> 1;
  stage_A_f32(emb, m0, As);
  __syncthreads();
  f32x4 acc[4];
  f32x4 zz = {0.f, 0.f, 0.f, 0.f};
  acc[0] = zz; acc[1] = zz; acc[2] = zz; acc[3] = zz;
  mfma_accum(As, W, rt, ch, quad, r16, acc);
  float pg[4] = {};
#pragma unroll
  for (int nt = 0; nt < 4; ++nt) {
    float wv = w2[ch * 64 + nt * 16 + r16];
#pragma unroll
    for (int g = 0; g < 4; ++g) pg[g] += fmaxf(acc[nt][g], 0.f) * wv;
  }
#pragma unroll
  for (int mask = 1; mask < 16; mask <<= 1)
#pragma unroll
    for (int g = 0; g < 4; ++g) pg[g] += __shfl_xor(pg[g], mask);
  if (r16 == 0) {
#pragma unroll
    for (int g = 0; g < 4; ++g) part[rt * 16 + quad * 4 + g][ch] = pg[g];
  }
  __syncthreads();
  if (t < 32) {
    float sv = part[t][0] + part[t][1];
    pbuf[m0 + t] = 1.f / (1.f + __expf(-sv));
  }
}

// ---------------- edge prediction ----------------
__global__ void pred_kernel(const float* __restrict__ p, const int* __restrict__ eli,
                            float* __restrict__ out, int K) {
  int i = blockIdx.x * blockDim.x + threadIdx.x;
  if (i < K) out[i] = p[eli[i]] * p[eli[K + i]];
}

extern "C" void kernel_launch(void* const* d_in, const int* in_sizes, int n_in,
                              void* d_out, int out_size, void* d_ws, size_t ws_size,
                              hipStream_t stream) {
  const float* x       = (const float*)d_in[0];
  const float* seq     = (const float*)d_in[1];
  const int* src       = (const int*)d_in[2];
  const int* dst       = (const int*)d_in[3];
  const int* eli       = (const int*)d_in[4];
  const float* skip_w0 = (const float*)d_in[5];
  const float* skip_b0 = (const float*)d_in[6];
  const float* msg_w0  = (const float*)d_in[7];
  const float* msg_b0  = (const float*)d_in[8];
  const float* skip_w1 = (const float*)d_in[9];
  const float* skip_b1 = (const float*)d_in[10];
  const float* msg_w1  = (const float*)d_in[11];
  const float* msg_b1  = (const float*)d_in[12];
  const float* ipw     = (const float*)d_in[13];
  const float* ipb     = (const float*)d_in[14];
  const float* opw     = (const float*)d_in[15];
  const float* opb     = (const float*)d_in[16];
  const float* ln_g    = (const float*)d_in[17];
  const float* ln_b    = (const float*)d_in[18];
  const float* w1      = (const float*)d_in[19];
  const float* w2      = (const float*)d_in[20];

  const int N  = in_sizes[0] / D;   // 8192
  const int S  = in_sizes[1] / D;   // 2048
  const int E  = in_sizes[2];       // 524288
  const int Kp = in_sizes[4] / 2;   // 100000

  float* ws    = (float*)d_ws;
  float* B2    = ws;                                   // N*D
  float* Osp   = B2 + (size_t)N * D;                   // SPLITS*N*D
  short* xbf   = (short*)(Osp + (size_t)SPLITS * N * D);
  short* Abf   = xbf + (size_t)N * D;
  short* B1bf  = Abf + (size_t)N * D;
  short* Qbf   = B1bf + (size_t)N * D;
  short* Kbf   = Qbf + (size_t)N * D;
  short* Vt    = Kbf + (size_t)S * D;
  short* Wbf   = Vt + (size_t)D * S;                   // 9*16384
  float* qn    = (float*)(Wbf + 9 * 16384);            // 4N
  float* lbuf  = qn + 4 * (size_t)N;                   // 4*SPLITS*N
  float* dinv  = lbuf + 4 * (size_t)SPLITS * N;
  float* pbuf  = dinv + N;
  int*   MkhI  = (int*)(pbuf + N);                     // 4
  int*   deg   = MkhI + 4;                             // N
  int* row_ptr = deg + N;                              // N+1
  int* csr_src = row_ptr + (N + 1);                    // E
  int* histd   = csr_src + E;                          // HB*8192
  int* hists   = histd + HB * 8192;                    // HB*8192
  int* base_arr= hists + HB * 8192;                    // HB*8192

  float* pred_out = (float*)d_out;
  float* emb_out  = pred_out + Kp;

  const short* w_skip0 = Wbf + 0 * 16384;
  const short* w_msg0  = Wbf + 1 * 16384;
  const short* w_skip1 = Wbf + 2 * 16384;
  const short* w_msg1  = Wbf + 3 * 16384;
  const short* w_q     = Wbf + 4 * 16384;
  const short* w_k     = Wbf + 5 * 16384;
  const short* w_v     = Wbf + 6 * 16384;
  const short* w_op    = Wbf + 7 * 16384;
  const short* w_m1    = Wbf + 8 * 16384;

  WSrc wsrc;
  wsrc.p[0] = skip_w0; wsrc.p[1] = msg_w0; wsrc.p[2] = skip_w1; wsrc.p[3] = msg_w1;
  wsrc.p[4] = ipw; wsrc.p[5] = ipw + D * D; wsrc.p[6] = ipw + 2 * D * D;
  wsrc.p[7] = opw; wsrc.p[8] = w1;
  prep0_kernel<<<144 + (N * D / 1024), 256, 0, stream>>>(wsrc, (short*)Wbf, x, xbf, MkhI);

  // atomic-free CSR build (5 kernels, each at its natural parallelism)
  hist_kernel<<<HB, 256, 0, stream>>>(src, dst, histd, hists, E);
  colsum_kernel<<<N / 256, 256, 0, stream>>>(histd, hists, deg, dinv);
  scan8k_kernel<<<1, 1024, 0, stream>>>(deg, row_ptr, N);
  basegen_kernel<<<N / 256, 256, 0, stream>>>(histd, row_ptr, base_arr);
  scatter2_kernel<<<HB, 256, 0, stream>>>(src, dst, base_arr, csr_src, E);

  // GCN layers
  agg_kernel<<<N, 128, 0, stream>>>(xbf, dinv, row_ptr, csr_src, Abf);
  gemm_gcn_kernel<<<N / 32, 256, 0, stream>>>(Abf, w_msg0, msg_b0, xbf, w_skip0, skip_b0, B1bf, nullptr);
  agg_kernel<<<N, 128, 0, stream>>>(B1bf, dinv, row_ptr, csr_src, Abf);
  gemm_gcn_kernel<<<N / 32, 256, 0, stream>>>(Abf, w_msg1, msg_b1, B1bf, w_skip1, skip_b1, nullptr, B2);

  // fused QKV + attention prep
  qkv_kernel<<<N / 32 + 2 * (S / 32), 256, 0, stream>>>(
      B2, seq, w_q, w_k, w_v, ipb, Qbf, qn, Kbf, MkhI, Vt, N, S);

  // attention: split-S=8, plain stores, merge fused into out_proj GEMM
  dim3 fgrid(N / 32, 4, SPLITS);
  flash_kernel<<<fgrid, 64, 0, stream>>>(Qbf, Kbf, Vt, qn, MkhI, Osp, lbuf, N, S);
  gemm_op_kernel<<<N / 32, 256, 0, stream>>>(Osp, lbuf, w_op, opb, B2, ln_g, ln_b, emb_out, N);

  // MLP (+sigmoid) and prediction
  gemm_mlp_kernel<<<N / 32, 256, 0, stream>>>(emb_out, w_m1, w2, pbuf);
  pred_kernel<<<(Kp + 255) / 256, 256, 0, stream>>>(pbuf, eli, pred_out, Kp);
}

// Round 9
// 234.741 us; speedup vs baseline: 1.5212x; 1.2160x over previous
//
#include <hip/hip_runtime.h>
#include <math.h>

#define D 128
#define HB 128     // histogram blocks
#define FA_PS 88   // flash P stride (shorts)
#define SPLITS 4

typedef short bf16x4 __attribute__((ext_vector_type(4)));
typedef short bf16x8 __attribute__((ext_vector_type(8)));
typedef float f32x4 __attribute__((ext_vector_type(4)));

__device__ __forceinline__ float4 ld4(const float* p) { return *(const float4*)p; }

__device__ __forceinline__ short f2bf_r(float f) {
  return (short)((__float_as_uint(f) + 0x8000u) >> 16);
}
__device__ __forceinline__ float bf2f(short s) {
  return __uint_as_float(((unsigned)(unsigned short)s) << 16);
}
__device__ __forceinline__ unsigned pack_bf2(float a, float b) {
  unsigned ua = __float_as_uint(a) + 0x8000u;
  unsigned ub = __float_as_uint(b) + 0x8000u;
  return __builtin_amdgcn_perm(ub, ua, 0x07060302);
}

// ---------------- prep0: weights + x -> bf16; zero MkhI ----------------
struct WSrc { const float* p[9]; };
__global__ __launch_bounds__(256) void prep0_kernel(WSrc ws, short* __restrict__ Wbf,
                                                    const float* __restrict__ x,
                                                    short* __restrict__ xbf,
                                                    int* __restrict__ MkhI) {
  int b = blockIdx.x, t = threadIdx.x;
  if (b == 0 && t < 4) MkhI[t] = 0;
  if (b < 144) {
    int m = b >> 4, blk = b & 15;
    int i = (blk * 256 + t) * 4;
    float4 v = ld4(ws.p[m] + i);
    bf16x4 o = {f2bf_r(v.x), f2bf_r(v.y), f2bf_r(v.z), f2bf_r(v.w)};
    *(bf16x4*)&Wbf[m * 16384 + i] = o;
  } else {
    int i = ((b - 144) * 256 + t) * 4;
    float4 v = ld4(x + i);
    bf16x4 o = {f2bf_r(v.x), f2bf_r(v.y), f2bf_r(v.z), f2bf_r(v.w)};
    *(bf16x4*)&xbf[i] = o;
  }
}

// ---------------- CSR build, atomic-free (LDS-privatized histograms), 5 kernels ----------------
__global__ __launch_bounds__(256) void hist_kernel(
    const int* __restrict__ src, const int* __restrict__ dst,
    int* __restrict__ histd, int* __restrict__ hists, int E) {
  __shared__ int hd[8192];
  __shared__ int hs[8192];
  int t = threadIdx.x;
  for (int i = t; i < 8192; i += 256) { hd[i] = 0; hs[i] = 0; }
  __syncthreads();
  int per = E / HB;
  int b0 = blockIdx.x * per;
  for (int j = 0; j < per; j += 256) {
    int i = b0 + j + t;
    atomicAdd(&hd[dst[i]], 1);
    atomicAdd(&hs[src[i]], 1);
  }
  __syncthreads();
  for (int i = t; i < 8192; i += 256) {
    histd[blockIdx.x * 8192 + i] = hd[i];
    hists[blockIdx.x * 8192 + i] = hs[i];
  }
}

__global__ __launch_bounds__(256) void colsum_kernel(
    const int* __restrict__ histd, const int* __restrict__ hists,
    int* __restrict__ deg, float* __restrict__ dinv) {
  int v = blockIdx.x * 256 + threadIdx.x;
  int sd = 0, ss = 0;
  for (int b = 0; b < HB; ++b) { sd += histd[b * 8192 + v]; ss += hists[b * 8192 + v]; }
  deg[v] = sd;
  dinv[v] = ss > 0 ? rsqrtf((float)ss) : 0.f;
}

__global__ __launch_bounds__(1024) void scan8k_kernel(
    const int* __restrict__ deg, int* __restrict__ row_ptr, int N) {
  __shared__ int wtot[16];
  int t = threadIdx.x;
  int lane = t & 63, wv = t >> 6;
  int v0 = t * 8;
  int x[8]; int s = 0;
#pragma unroll
  for (int j = 0; j < 8; ++j) { x[j] = s; s += deg[v0 + j]; }
  int incl = s;
  for (int off = 1; off < 64; off <<= 1) {
    int y = __shfl_up(incl, off);
    if (lane >= off) incl += y;
  }
  if (lane == 63) wtot[wv] = incl;
  __syncthreads();
  if (t == 0) { int run = 0; for (int i = 0; i < 16; ++i) { int v = wtot[i]; wtot[i] = run; run += v; } }
  __syncthreads();
  int base = wtot[wv] + (incl - s);
#pragma unroll
  for (int j = 0; j < 8; ++j) row_ptr[v0 + j] = base + x[j];
  if (t == 1023) row_ptr[N] = base + s;
}

__global__ __launch_bounds__(256) void basegen_kernel(
    const int* __restrict__ histd, const int* __restrict__ row_ptr,
    int* __restrict__ base_arr) {
  int v = blockIdx.x * 256 + threadIdx.x;
  int run = row_ptr[v];
  for (int b = 0; b < HB; ++b) { base_arr[b * 8192 + v] = run; run += histd[b * 8192 + v]; }
}

__global__ __launch_bounds__(256) void scatter2_kernel(
    const int* __restrict__ src, const int* __restrict__ dst,
    const int* __restrict__ base_arr, int* __restrict__ csr_src, int E) {
  __shared__ int lh[8192];
  int t = threadIdx.x;
  for (int i = t; i < 8192; i += 256) lh[i] = 0;
  __syncthreads();
  int per = E / HB;
  int b0 = blockIdx.x * per;
  const int* __restrict__ bb = &base_arr[blockIdx.x * 8192];
  for (int j = 0; j < per; j += 256) {
    int i = b0 + j + t;
    int v = dst[i];
    int r = atomicAdd(&lh[v], 1);
    csr_src[bb[v] + r] = src[i];
  }
}

// ---------------- GCN aggregation: bf16 gather, 4 independent edge streams ----------------
__global__ __launch_bounds__(128) void agg_kernel(
    const short* __restrict__ fbf, const float* __restrict__ dinv,
    const int* __restrict__ row_ptr, const int* __restrict__ csr_src,
    short* __restrict__ outbf) {
  __shared__ int idx[128];
  __shared__ float dv[128];
  __shared__ float red[8][128];
  int n = blockIdx.x, t = threadIdx.x;
  int grp = t >> 4, l16 = t & 15;
  int beg = row_ptr[n], end = row_ptr[n + 1];
  float a0[8] = {}, a1[8] = {}, a2[8] = {}, a3[8] = {};
  for (int c = beg; c < end; c += 128) {
    int j = c + t;
    if (j < end) { int s = csr_src[j]; idx[t] = s; dv[t] = dinv[s]; }
    __syncthreads();
    int cnt = min(128, end - c);
    int e = grp;
    for (; e + 24 < cnt; e += 32) {
      bf16x8 w0 = *(const bf16x8*)&fbf[(size_t)idx[e] * D + l16 * 8];
      bf16x8 w1 = *(const bf16x8*)&fbf[(size_t)idx[e + 8] * D + l16 * 8];
      bf16x8 w2 = *(const bf16x8*)&fbf[(size_t)idx[e + 16] * D + l16 * 8];
      bf16x8 w3 = *(const bf16x8*)&fbf[(size_t)idx[e + 24] * D + l16 * 8];
      float wt0 = dv[e], wt1 = dv[e + 8], wt2 = dv[e + 16], wt3 = dv[e + 24];
#pragma unroll
      for (int k = 0; k < 8; ++k) {
        a0[k] += bf2f(w0[k]) * wt0;
        a1[k] += bf2f(w1[k]) * wt1;
        a2[k] += bf2f(w2[k]) * wt2;
        a3[k] += bf2f(w3[k]) * wt3;
      }
    }
    for (; e < cnt; e += 8) {
      bf16x8 w0 = *(const bf16x8*)&fbf[(size_t)idx[e] * D + l16 * 8];
      float wt0 = dv[e];
#pragma unroll
      for (int k = 0; k < 8; ++k) a0[k] += bf2f(w0[k]) * wt0;
    }
    __syncthreads();
  }
#pragma unroll
  for (int k = 0; k < 8; ++k) a0[k] += a1[k] + a2[k] + a3[k];
  *(float4*)&red[grp][l16 * 8] = *(float4*)&a0[0];
  *(float4*)&red[grp][l16 * 8 + 4] = *(float4*)&a0[4];
  __syncthreads();
  if (t < 32) {
    int d0 = t * 4;
    float o[4] = {};
#pragma unroll
    for (int g = 0; g < 8; ++g) {
      o[0] += red[g][d0]; o[1] += red[g][d0 + 1];
      o[2] += red[g][d0 + 2]; o[3] += red[g][d0 + 3];
    }
    float w = dinv[n];
    bf16x4 ov = {f2bf_r(o[0] * w), f2bf_r(o[1] * w), f2bf_r(o[2] * w), f2bf_r(o[3] * w)};
    *(bf16x4*)&outbf[(size_t)n * D + d0] = ov;
  }
}

// ---------------- MFMA helpers ----------------
__device__ __forceinline__ void mfma_accum(const short* As, const short* __restrict__ W,
                                           int rt, int ch, int quad, int r16, f32x4* acc) {
#pragma unroll
  for (int ks = 0; ks < 4; ++ks) {
    bf16x8 af = *(bf16x8*)&As[(rt * 16 + r16) * 136 + ks * 32 + quad * 8];
#pragma unroll
    for (int nt = 0; nt < 4; ++nt) {
      bf16x8 bw = *(const bf16x8*)&W[(size_t)(ch * 64 + nt * 16 + r16) * D + ks * 32 + quad * 8];
      acc[nt] = __builtin_amdgcn_mfma_f32_16x16x32_bf16(af, bw, acc[nt], 0, 0, 0);
    }
  }
}

__device__ __forceinline__ void stage_A_f32(const float* __restrict__ A, int m0, short* As) {
  int row = threadIdx.x >> 3, seg = threadIdx.x & 7;
  const float* ap = &A[(size_t)(m0 + row) * D + seg * 16];
  float4 v0 = ld4(ap), v1 = ld4(ap + 4), v2 = ld4(ap + 8), v3 = ld4(ap + 12);
  bf16x8 w0 = {f2bf_r(v0.x), f2bf_r(v0.y), f2bf_r(v0.z), f2bf_r(v0.w),
               f2bf_r(v1.x), f2bf_r(v1.y), f2bf_r(v1.z), f2bf_r(v1.w)};
  bf16x8 w1 = {f2bf_r(v2.x), f2bf_r(v2.y), f2bf_r(v2.z), f2bf_r(v2.w),
               f2bf_r(v3.x), f2bf_r(v3.y), f2bf_r(v3.z), f2bf_r(v3.w)};
  *(bf16x8*)&As[row * 136 + seg * 16] = w0;
  *(bf16x8*)&As[row * 136 + seg * 16 + 8] = w1;
}

__device__ __forceinline__ void stage_A_bf16(const short* __restrict__ A, int m0, short* As) {
  int row = threadIdx.x >> 3, seg = threadIdx.x & 7;
  const short* ap = &A[(size_t)(m0 + row) * D + seg * 16];
  bf16x8 a0 = *(const bf16x8*)ap;
  bf16x8 a1 = *(const bf16x8*)(ap + 8);
  *(bf16x8*)&As[row * 136 + seg * 16] = a0;
  *(bf16x8*)&As[row * 136 + seg * 16 + 8] = a1;
}

// ---------------- GCN dual GEMM ----------------
__global__ __launch_bounds__(256) void gemm_gcn_kernel(
    const short* __restrict__ A1, const short* __restrict__ W1, const float* __restrict__ b1,
    const short* __restrict__ A2, const short* __restrict__ W2, const float* __restrict__ b2,
    short* __restrict__ Cbf, float* __restrict__ Cf) {
  __shared__ short As[32 * 136];
  const int t = threadIdx.x;
  const int m0 = blockIdx.x * 32;
  const int w = t >> 6, lane = t & 63, quad = lane >> 4, r16 = lane & 15;
  const int rt = w & 1, ch = w >> 1;
  f32x4 acc[4];
  f32x4 zz = {0.f, 0.f, 0.f, 0.f};
  acc[0] = zz; acc[1] = zz; acc[2] = zz; acc[3] = zz;
  stage_A_bf16(A1, m0, As);
  __syncthreads();
  mfma_accum(As, W1, rt, ch, quad, r16, acc);
  __syncthreads();
  stage_A_bf16(A2, m0, As);
  __syncthreads();
  mfma_accum(As, W2, rt, ch, quad, r16, acc);
#pragma unroll
  for (int nt = 0; nt < 4; ++nt) {
    int col = ch * 64 + nt * 16 + r16;
    float bias = b1[col] + b2[col];
#pragma unroll
    for (int g = 0; g < 4; ++g) {
      int row = m0 + rt * 16 + quad * 4 + g;
      float v = acc[nt][g] + bias;
      if (Cbf) Cbf[(size_t)row * D + col] = f2bf_r(v);
      if (Cf) Cf[(size_t)row * D + col] = v;
    }
  }
}

// ---------------- fused QKV projections with prep epilogues ----------------
// Q -> Qh[h][row][32] head-major + qn; K -> Kh[h][key][32] head-major + MkhI; V -> Vt permuted
__global__ __launch_bounds__(256) void qkv_kernel(
    const float* __restrict__ B2, const float* __restrict__ seq,
    const short* __restrict__ Wq, const short* __restrict__ Wk, const short* __restrict__ Wv,
    const float* __restrict__ ipb,
    short* __restrict__ Qh, float* __restrict__ qn,
    short* __restrict__ Kh, int* __restrict__ MkhI,
    short* __restrict__ Vt, int N, int S) {
  __shared__ short As[32 * 136];
  __shared__ int lmax[4];
  const int t = threadIdx.x;
  const int b = blockIdx.x;
  const int w = t >> 6, lane = t & 63, quad = lane >> 4, r16 = lane & 15;
  const int rt = w & 1, ch = w >> 1;
  if (t < 4) lmax[t] = 0;
  f32x4 acc[4];
  f32x4 zz = {0.f, 0.f, 0.f, 0.f};
  acc[0] = zz; acc[1] = zz; acc[2] = zz; acc[3] = zz;
  const float SC = 0.25503473f;   // (1/sqrt(32)) * log2(e)

  if (b < 256) {
    int m0 = b * 32;
    stage_A_f32(B2, m0, As);
    __syncthreads();
    mfma_accum(As, Wq, rt, ch, quad, r16, acc);
    float pq[4][2] = {};
#pragma unroll
    for (int nt = 0; nt < 4; ++nt) {
      int col = ch * 64 + nt * 16 + r16;
      int hq = col >> 5, dq = col & 31;
      float bias = ipb[col];
      int p = nt >> 1;
#pragma unroll
      for (int g = 0; g < 4; ++g) {
        int row = m0 + rt * 16 + quad * 4 + g;
        float vs = (acc[nt][g] + bias) * SC;
        Qh[((size_t)hq * N + row) * 32 + dq] = f2bf_r(vs);
        pq[g][p] += vs * vs;
      }
    }
#pragma unroll
    for (int mask = 1; mask < 16; mask <<= 1)
#pragma unroll
      for (int g = 0; g < 4; ++g) {
        pq[g][0] += __shfl_xor(pq[g][0], mask);
        pq[g][1] += __shfl_xor(pq[g][1], mask);
      }
    if (r16 == 0) {
#pragma unroll
      for (int g = 0; g < 4; ++g) {
        int row = m0 + rt * 16 + quad * 4 + g;
        qn[(ch * 2 + 0) * N + row] = sqrtf(pq[g][0]);
        qn[(ch * 2 + 1) * N + row] = sqrtf(pq[g][1]);
      }
    }
  } else if (b < 320) {
    int m0 = (b - 256) * 32;
    stage_A_f32(seq, m0, As);
    __syncthreads();
    mfma_accum(As, Wk, rt, ch, quad, r16, acc);
    float pk[4][2] = {};
#pragma unroll
    for (int nt = 0; nt < 4; ++nt) {
      int col = ch * 64 + nt * 16 + r16;
      int hk = col >> 5, dk = col & 31;
      float bias = ipb[128 + col];
      int p = nt >> 1;
#pragma unroll
      for (int g = 0; g < 4; ++g) {
        int key = m0 + rt * 16 + quad * 4 + g;
        float v = acc[nt][g] + bias;
        Kh[((size_t)hk * S + key) * 32 + dk] = f2bf_r(v);
        pk[g][p] += v * v;
      }
    }
#pragma unroll
    for (int mask = 1; mask < 16; mask <<= 1)
#pragma unroll
      for (int g = 0; g < 4; ++g) {
        pk[g][0] += __shfl_xor(pk[g][0], mask);
        pk[g][1] += __shfl_xor(pk[g][1], mask);
      }
    if (r16 == 0) {
#pragma unroll
      for (int g = 0; g < 4; ++g) {
        atomicMax(&lmax[ch * 2 + 0], __float_as_int(pk[g][0]));
        atomicMax(&lmax[ch * 2 + 1], __float_as_int(pk[g][1]));
      }
    }
    __syncthreads();
    if (t < 4) atomicMax(&MkhI[t], lmax[t]);
  } else {
    int m0 = (b - 320) * 32;
    stage_A_f32(seq, m0, As);
    __syncthreads();
    mfma_accum(As, Wv, rt, ch, quad, r16, acc);
#pragma unroll
    for (int nt = 0; nt < 4; ++nt) {
      int dim = ch * 64 + nt * 16 + r16;
      float bias = ipb[256 + dim];
#pragma unroll
      for (int g = 0; g < 4; ++g) {
        int s = m0 + rt * 16 + quad * 4 + g;
        int local = s & 63;
        int kp = (local & 15) * 4 + (local >> 4);     // key' permutation
        int gcol = (s & ~63) + kp;
        Vt[(size_t)dim * S + gcol] = f2bf_r(acc[nt][g] + bias);
      }
    }
  }
}

// ---------------- MFMA flash attention: fixed-shift (log2), split-S=4, head-major Q/K ----------------
__global__ __launch_bounds__(64, 4) void flash_kernel(
    const short* __restrict__ Qh, const short* __restrict__ Kh, const short* __restrict__ Vt,
    const float* __restrict__ qn, const int* __restrict__ MkhI,
    float* __restrict__ Osp, float* __restrict__ lbuf, int N, int S) {
  __shared__ short Ps[32 * FA_PS];
  const int lane = threadIdx.x;
  const int quad = lane >> 4, r16 = lane & 15;
  const int n0 = blockIdx.x * 32;
  const int h = blockIdx.y;
  const int sp = blockIdx.z;
  float* O = Osp + (size_t)sp * N * D;
  const short* Kb = Kh + (size_t)h * S * 32;
  const short* Qb = Qh + (size_t)h * N * 32;

  bf16x8 aq[2];
  aq[0] = *(const bf16x8*)&Qb[(size_t)(n0 + r16) * 32 + quad * 8];
  aq[1] = *(const bf16x8*)&Qb[(size_t)(n0 + 16 + r16) * 32 + quad * 8];

  float sqm = sqrtf(fmaxf(__int_as_float(MkhI[h]), 0.f));
  float msh[2][4];
#pragma unroll
  for (int rt = 0; rt < 2; ++rt)
#pragma unroll
    for (int g = 0; g < 4; ++g)
      msh[rt][g] = fminf(qn[h * N + n0 + rt * 16 + quad * 4 + g] * sqm, 57.7f);

  f32x4 o[2][2], lac[2];
  f32x4 zz = {0.f, 0.f, 0.f, 0.f};
  o[0][0] = zz; o[0][1] = zz; o[1][0] = zz; o[1][1] = zz;
  lac[0] = zz; lac[1] = zz;
  bf16x8 ones = {(short)0x3F80, (short)0x3F80, (short)0x3F80, (short)0x3F80,
                 (short)0x3F80, (short)0x3F80, (short)0x3F80, (short)0x3F80};

  const int span = S / SPLITS;
  const int c0 = sp * span;
  for (int c = c0; c < c0 + span; c += 64) {
    f32x4 s[2][4];
#pragma unroll
    for (int kt = 0; kt < 4; ++kt) {
      bf16x8 bk = *(const bf16x8*)&Kb[(size_t)(c + kt * 16 + r16) * 32 + quad * 8];
      f32x4 z = {0.f, 0.f, 0.f, 0.f};
      s[0][kt] = __builtin_amdgcn_mfma_f32_16x16x32_bf16(aq[0], bk, z, 0, 0, 0);
      s[1][kt] = __builtin_amdgcn_mfma_f32_16x16x32_bf16(aq[1], bk, z, 0, 0, 0);
    }
#pragma unroll
    for (int rt = 0; rt < 2; ++rt)
#pragma unroll
      for (int g = 0; g < 4; ++g) {
        float m = msh[rt][g];
        float p0 = exp2f(s[rt][0][g] - m);
        float p1 = exp2f(s[rt][1][g] - m);
        float p2 = exp2f(s[rt][2][g] - m);
        float p3 = exp2f(s[rt][3][g] - m);
        uint2 uv = {pack_bf2(p0, p1), pack_bf2(p2, p3)};
        *(uint2*)&Ps[(rt * 16 + quad * 4 + g) * FA_PS + r16 * 4] = uv;
      }
    bf16x8 bv[2][2];
#pragma unroll
    for (int kc = 0; kc < 2; ++kc)
#pragma unroll
      for (int nt = 0; nt < 2; ++nt)
        bv[kc][nt] = *(const bf16x8*)&Vt[(size_t)(h * 32 + nt * 16 + r16) * S + c + kc * 32 + quad * 8];
#pragma unroll
    for (int rt = 0; rt < 2; ++rt)
#pragma unroll
      for (int kc = 0; kc < 2; ++kc) {
        bf16x8 ap = *(bf16x8*)&Ps[(rt * 16 + r16) * FA_PS + kc * 32 + quad * 8];
        lac[rt] = __builtin_amdgcn_mfma_f32_16x16x32_bf16(ap, ones, lac[rt], 0, 0, 0);
#pragma unroll
        for (int nt = 0; nt < 2; ++nt)
          o[rt][nt] = __builtin_amdgcn_mfma_f32_16x16x32_bf16(ap, bv[kc][nt], o[rt][nt], 0, 0, 0);
      }
  }
#pragma unroll
  for (int rt = 0; rt < 2; ++rt)
#pragma unroll
    for (int g = 0; g < 4; ++g) {
      int row = n0 + rt * 16 + quad * 4 + g;
#pragma unroll
      for (int nt = 0; nt < 2; ++nt)
        O[(size_t)row * D + h * 32 + nt * 16 + r16] = o[rt][nt][g];
      if (r16 == 0) lbuf[(sp * 4 + h) * N + row] = lac[rt][g];
    }
}

// ---------------- out_proj GEMM: fused split-merge + residual + LN + L2 ----------------
__global__ __launch_bounds__(256) void gemm_op_kernel(
    const float* __restrict__ Osp, const float* __restrict__ lbuf,
    const short* __restrict__ W, const float* __restrict__ bias,
    const float* __restrict__ Rres, const float* __restrict__ ln_g,
    const float* __restrict__ ln_b, float* __restrict__ emb, int N) {
  __shared__ short As[32 * 136];
  __shared__ float Cs[32 * 132];
  const int t = threadIdx.x;
  const int m0 = blockIdx.x * 32;
  const int w = t >> 6, lane = t & 63, quad = lane >> 4, r16 = lane & 15;
  const int rt = w & 1, ch = w >> 1;
  {
    int row = t >> 3, seg = t & 7;
    int grow = m0 + row;
    int hh = seg >> 1;
    float l = 0.f;
#pragma unroll
    for (int s = 0; s < SPLITS; ++s) l += lbuf[(s * 4 + hh) * N + grow];
    float inv = 1.f / l;
    const float* p = &Osp[(size_t)grow * D + seg * 16];
    size_t st = (size_t)N * D;
    float a16[16] = {};
#pragma unroll
    for (int s = 0; s < SPLITS; ++s) {
#pragma unroll
      for (int q = 0; q < 4; ++q) {
        float4 a = ld4(p + s * st + q * 4);
        a16[q * 4 + 0] += a.x; a16[q * 4 + 1] += a.y;
        a16[q * 4 + 2] += a.z; a16[q * 4 + 3] += a.w;
      }
    }
#pragma unroll
    for (int k = 0; k < 16; ++k) a16[k] *= inv;
    bf16x8 w0 = {f2bf_r(a16[0]), f2bf_r(a16[1]), f2bf_r(a16[2]), f2bf_r(a16[3]),
                 f2bf_r(a16[4]), f2bf_r(a16[5]), f2bf_r(a16[6]), f2bf_r(a16[7])};
    bf16x8 w1 = {f2bf_r(a16[8]), f2bf_r(a16[9]), f2bf_r(a16[10]), f2bf_r(a16[11]),
                 f2bf_r(a16[12]), f2bf_r(a16[13]), f2bf_r(a16[14]), f2bf_r(a16[15])};
    *(bf16x8*)&As[row * 136 + seg * 16] = w0;
    *(bf16x8*)&As[row * 136 + seg * 16 + 8] = w1;
  }
  __syncthreads();
  f32x4 acc[4];
  f32x4 zz = {0.f, 0.f, 0.f, 0.f};
  acc[0] = zz; acc[1] = zz; acc[2] = zz; acc[3] = zz;
  mfma_accum(As, W, rt, ch, quad, r16, acc);
#pragma unroll
  for (int nt = 0; nt < 4; ++nt) {
    int col = ch * 64 + nt * 16 + r16;
    float bs = bias[col];
#pragma unroll
    for (int g = 0; g < 4; ++g) {
      int lr = rt * 16 + quad * 4 + g;
      Cs[lr * 132 + col] = acc[nt][g] + bs + Rres[(size_t)(m0 + lr) * D + col];
    }
  }
  __syncthreads();
  {
    int row = t >> 3, seg = t & 7;
    float xv[16];
#pragma unroll
    for (int q = 0; q < 4; ++q) {
      f32x4 v = *(f32x4*)&Cs[row * 132 + seg * 16 + q * 4];
      xv[q * 4] = v[0]; xv[q * 4 + 1] = v[1]; xv[q * 4 + 2] = v[2]; xv[q * 4 + 3] = v[3];
    }
    float s = 0.f, sq = 0.f;
#pragma unroll
    for (int k = 0; k < 16; ++k) { s += xv[k]; sq += xv[k] * xv[k]; }
#pragma unroll
    for (int mask = 1; mask < 8; mask <<= 1) { s += __shfl_xor(s, mask); sq += __shfl_xor(sq, mask); }
    float mu = s * (1.f / 128.f);
    float var = fmaxf(sq * (1.f / 128.f) - mu * mu, 0.f);
    float rs = rsqrtf(var + 1e-5f);
    float yv[16], nn = 0.f;
#pragma unroll
    for (int q = 0; q < 4; ++q) {
      float4 gg = ld4(&ln_g[seg * 16 + q * 4]);
      float4 bb = ld4(&ln_b[seg * 16 + q * 4]);
      float y0 = (xv[q * 4] - mu) * rs * gg.x + bb.x;
      float y1 = (xv[q * 4 + 1] - mu) * rs * gg.y + bb.y;
      float y2 = (xv[q * 4 + 2] - mu) * rs * gg.z + bb.z;
      float y3 = (xv[q * 4 + 3] - mu) * rs * gg.w + bb.w;
      yv[q * 4] = y0; yv[q * 4 + 1] = y1; yv[q * 4 + 2] = y2; yv[q * 4 + 3] = y3;
      nn += y0 * y0 + y1 * y1 + y2 * y2 + y3 * y3;
    }
#pragma unroll
    for (int mask = 1; mask < 8; mask <<= 1) nn += __shfl_xor(nn, mask);
    float inv = 1.f / fmaxf(sqrtf(nn), 1e-12f);
#pragma unroll
    for (int q = 0; q < 4; ++q) {
      float4 ov = {yv[q * 4] * inv, yv[q * 4 + 1] * inv, yv[q * 4 + 2] * inv, yv[q * 4 + 3] * inv};
      *(float4*)&emb[(size_t)(m0 + row) * D + seg * 16 + q * 4] = ov;
    }
  }
}

// ---------------- MLP GEMM fused with sigmoid ----------------
__global__ __launch_bounds__(256) void gemm_mlp_kernel(
    const float* __restrict__ emb, const short* __restrict__ W,
    const float* __restrict__ w2, float* __restrict__ pbuf) {
  __shared__ short As[32 * 136];
  __shared__ float part[32][2];
  const int t = threadIdx.x;
  const int m0 = blockIdx.x * 32;
  const int w = t >> 6, lane = t & 63, quad = lane >> 4, r16 = lane & 15;
  const int rt = w & 1, ch = w >> 1;
  stage_A_f32(emb, m0, As);
  __syncthreads();
  f32x4 acc[4];
  f32x4 zz = {0.f, 0.f, 0.f, 0.f};
  acc[0] = zz; acc[1] = zz; acc[2] = zz; acc[3] = zz;
  mfma_accum(As, W, rt, ch, quad, r16, acc);
  float pg[4] = {};
#pragma unroll
  for (int nt = 0; nt < 4; ++nt) {
    float wv = w2[ch * 64 + nt * 16 + r16];
#pragma unroll
    for (int g = 0; g < 4; ++g) pg[g] += fmaxf(acc[nt][g], 0.f) * wv;
  }
#pragma unroll
  for (int mask = 1; mask < 16; mask <<= 1)
#pragma unroll
    for (int g = 0; g < 4; ++g) pg[g] += __shfl_xor(pg[g], mask);
  if (r16 == 0) {
#pragma unroll
    for (int g = 0; g < 4; ++g) part[rt * 16 + quad * 4 + g][ch] = pg[g];
  }
  __syncthreads();
  if (t < 32) {
    float sv = part[t][0] + part[t][1];
    pbuf[m0 + t] = 1.f / (1.f + __expf(-sv));
  }
}

// ---------------- edge prediction ----------------
__global__ void pred_kernel(const float* __restrict__ p, const int* __restrict__ eli,
                            float* __restrict__ out, int K) {
  int i = blockIdx.x * blockDim.x + threadIdx.x;
  if (i < K) out[i] = p[eli[i]] * p[eli[K + i]];
}

extern "C" void kernel_launch(void* const* d_in, const int* in_sizes, int n_in,
                              void* d_out, int out_size, void* d_ws, size_t ws_size,
                              hipStream_t stream) {
  const float* x       = (const float*)d_in[0];
  const float* seq     = (const float*)d_in[1];
  const int* src       = (const int*)d_in[2];
  const int* dst       = (const int*)d_in[3];
  const int* eli       = (const int*)d_in[4];
  const float* skip_w0 = (const float*)d_in[5];
  const float* skip_b0 = (const float*)d_in[6];
  const float* msg_w0  = (const float*)d_in[7];
  const float* msg_b0  = (const float*)d_in[8];
  const float* skip_w1 = (const float*)d_in[9];
  const float* skip_b1 = (const float*)d_in[10];
  const float* msg_w1  = (const float*)d_in[11];
  const float* msg_b1  = (const float*)d_in[12];
  const float* ipw     = (const float*)d_in[13];
  const float* ipb     = (const float*)d_in[14];
  const float* opw     = (const float*)d_in[15];
  const float* opb     = (const float*)d_in[16];
  const float* ln_g    = (const float*)d_in[17];
  const float* ln_b    = (const float*)d_in[18];
  const float* w1      = (const float*)d_in[19];
  const float* w2      = (const float*)d_in[20];

  const int N  = in_sizes[0] / D;   // 8192
  const int S  = in_sizes[1] / D;   // 2048
  const int E  = in_sizes[2];       // 524288
  const int Kp = in_sizes[4] / 2;   // 100000

  float* ws    = (float*)d_ws;
  float* B2    = ws;                                   // N*D
  float* Osp   = B2 + (size_t)N * D;                   // SPLITS*N*D
  short* xbf   = (short*)(Osp + (size_t)SPLITS * N * D);
  short* Abf   = xbf + (size_t)N * D;
  short* B1bf  = Abf + (size_t)N * D;
  short* Qh    = B1bf + (size_t)N * D;                 // head-major N*D
  short* Kh    = Qh + (size_t)N * D;                   // head-major S*D
  short* Vt    = Kh + (size_t)S * D;
  short* Wbf   = Vt + (size_t)D * S;                   // 9*16384
  float* qn    = (float*)(Wbf + 9 * 16384);            // 4N
  float* lbuf  = qn + 4 * (size_t)N;                   // 4*SPLITS*N
  float* dinv  = lbuf + 4 * (size_t)SPLITS * N;
  float* pbuf  = dinv + N;
  int*   MkhI  = (int*)(pbuf + N);                     // 4
  int*   deg   = MkhI + 4;                             // N
  int* row_ptr = deg + N;                              // N+1
  int* csr_src = row_ptr + (N + 1);                    // E
  int* histd   = csr_src + E;                          // HB*8192
  int* hists   = histd + HB * 8192;                    // HB*8192
  int* base_arr= hists + HB * 8192;                    // HB*8192

  float* pred_out = (float*)d_out;
  float* emb_out  = pred_out + Kp;

  const short* w_skip0 = Wbf + 0 * 16384;
  const short* w_msg0  = Wbf + 1 * 16384;
  const short* w_skip1 = Wbf + 2 * 16384;
  const short* w_msg1  = Wbf + 3 * 16384;
  const short* w_q     = Wbf + 4 * 16384;
  const short* w_k     = Wbf + 5 * 16384;
  const short* w_v     = Wbf + 6 * 16384;
  const short* w_op    = Wbf + 7 * 16384;
  const short* w_m1    = Wbf + 8 * 16384;

  WSrc wsrc;
  wsrc.p[0] = skip_w0; wsrc.p[1] = msg_w0; wsrc.p[2] = skip_w1; wsrc.p[3] = msg_w1;
  wsrc.p[4] = ipw; wsrc.p[5] = ipw + D * D; wsrc.p[6] = ipw + 2 * D * D;
  wsrc.p[7] = opw; wsrc.p[8] = w1;
  prep0_kernel<<<144 + (N * D / 1024), 256, 0, stream>>>(wsrc, (short*)Wbf, x, xbf, MkhI);

  // atomic-free CSR build (5 kernels, each at its natural parallelism)
  hist_kernel<<<HB, 256, 0, stream>>>(src, dst, histd, hists, E);
  colsum_kernel<<<N / 256, 256, 0, stream>>>(histd, hists, deg, dinv);
  scan8k_kernel<<<1, 1024, 0, stream>>>(deg, row_ptr, N);
  basegen_kernel<<<N / 256, 256, 0, stream>>>(histd, row_ptr, base_arr);
  scatter2_kernel<<<HB, 256, 0, stream>>>(src, dst, base_arr, csr_src, E);

  // GCN layers
  agg_kernel<<<N, 128, 0, stream>>>(xbf, dinv, row_ptr, csr_src, Abf);
  gemm_gcn_kernel<<<N / 32, 256, 0, stream>>>(Abf, w_msg0, msg_b0, xbf, w_skip0, skip_b0, B1bf, nullptr);
  agg_kernel<<<N, 128, 0, stream>>>(B1bf, dinv, row_ptr, csr_src, Abf);
  gemm_gcn_kernel<<<N / 32, 256, 0, stream>>>(Abf, w_msg1, msg_b1, B1bf, w_skip1, skip_b1, nullptr, B2);

  // fused QKV + attention prep (head-major Q/K)
  qkv_kernel<<<N / 32 + 2 * (S / 32), 256, 0, stream>>>(
      B2, seq, w_q, w_k, w_v, ipb, Qh, qn, Kh, MkhI, Vt, N, S);

  // attention: split-S=4, plain stores, merge fused into out_proj GEMM
  dim3 fgrid(N / 32, 4, SPLITS);
  flash_kernel<<<fgrid, 64, 0, stream>>>(Qh, Kh, Vt, qn, MkhI, Osp, lbuf, N, S);
  gemm_op_kernel<<<N / 32, 256, 0, stream>>>(Osp, lbuf, w_op, opb, B2, ln_g, ln_b, emb_out, N);

  // MLP (+sigmoid) and prediction
  gemm_mlp_kernel<<<N / 32, 256, 0, stream>>>(emb_out, w_m1, w2, pbuf);
  pred_kernel<<<(Kp + 255) / 256, 256, 0, stream>>>(pbuf, eli, pred_out, Kp);
}